// Round 5
// baseline (384.288 us; speedup 1.0000x reference)
//
#include <hip/hip_runtime.h>

// ---------------- helpers ----------------
typedef __attribute__((ext_vector_type(8))) short bf16x8;   // 8 bf16 (4 VGPRs)
typedef __attribute__((ext_vector_type(4))) float f32x4;

#define DEV static __device__ __forceinline__

DEV float b2f(unsigned short u) {
    union { unsigned int u; float f; } c; c.u = ((unsigned int)u) << 16; return c.f;
}
DEV unsigned short f2b(float f) {
    union { float f; unsigned int u; } c; c.f = f;
    unsigned int u = c.u + 0x7fffu + ((c.u >> 16) & 1u);
    return (unsigned short)(u >> 16);
}
DEV float silu_f(float v) { return v / (1.f + __expf(-v)); }

#define GLD16(gp, lp) __builtin_amdgcn_global_load_lds( \
    (const __attribute__((address_space(1))) void*)(gp), \
    (__attribute__((address_space(3))) void*)(lp), 16, 0, 0)

// sizes
#define LSEQ 2048
#define NB 2
#define RTOT 4096          // NB*LSEQ
#define DM 1024
#define DI 2048
#define NH 32
#define HP 64
#define NSTATE 16
#define CDIM 2080
#define DIP 4160           // per-dir in_proj width
#define NW 8320            // stacked width
#define QCH 128            // scan chunk length
#define NCH (LSEQ / QCH)   // 16 chunks

// ---------------- batched f32 -> bf16 convert ----------------
struct CvtJobs {
    const float* src[6];
    unsigned short* dst[6];
    int n4[6];
};
__global__ __launch_bounds__(256) void cvtb_kernel(CvtJobs j) {
    const int jb = blockIdx.y;
    const int i = blockIdx.x * 256 + threadIdx.x;
    if (i >= j.n4[jb]) return;
    float4 v = ((const float4*)j.src[jb])[i];
    union { unsigned short s[4]; uint2 u; } p;
    p.s[0] = f2b(v.x); p.s[1] = f2b(v.y); p.s[2] = f2b(v.z); p.s[3] = f2b(v.w);
    ((uint2*)j.dst[jb])[i] = p.u;
}

// ---------------- pipelined bf16 MFMA GEMM, template <BM,BN> ----------------
// BK=32, 8 waves (2M x 4N), 3 LDS tile-buffers, stage t+2 while computing t,
// counted vmcnt(GT) (never 0 mid-loop), T2 swizzle key (row^(row>>2))&3.
// A: M x K row-major; BT: N x K row-major. EPI 1 = bf16 store (clamped at Ntot);
// EPI 2 = f32 ex + v*esc. grid.z selects (A,BT,coff) for fused dual-GEMM.

#define BAR_WAIT \
    __builtin_amdgcn_s_barrier(); __builtin_amdgcn_sched_barrier(0); \
    asm volatile("s_waitcnt lgkmcnt(0)" ::: "memory"); \
    __builtin_amdgcn_sched_barrier(0);

#define ENDBAR \
    __builtin_amdgcn_s_barrier(); __builtin_amdgcn_sched_barrier(0);

template<int BM, int BN, int EPI>
__global__ void __launch_bounds__(512, (BM == 128 && BN == 128) ? 4 : 2)
gemmX_kernel(
    const unsigned short* __restrict__ A0, const unsigned short* __restrict__ BT0,
    const unsigned short* __restrict__ A1, const unsigned short* __restrict__ BT1,
    void* __restrict__ Cout,
    int Ntot, int K, int ldc, int coff0, int coff1,
    const float* __restrict__ ex, const float* __restrict__ esc)
{
    constexpr int MF = BM / 32;            // per-wave m-frags (per-wave M = BM/2)
    constexpr int NI = BN / 64;            // per-wave n-frags (per-wave N = BN/4)
    constexpr int GA = BM / 128, GB = BN / 128;
    constexpr int GT = GA + GB;            // gloads per tile per thread
    constexpr int ASH = BM * 32;           // shorts per A K32-tile
    constexpr int BSH = BN * 32;
    constexpr int BUF = ASH + BSH;
    __shared__ unsigned short lds[3 * BUF];

    const unsigned short* __restrict__ A  = blockIdx.z ? A1 : A0;
    const unsigned short* __restrict__ BT = blockIdx.z ? BT1 : BT0;
    const int coff = blockIdx.z ? coff1 : coff0;

    // bijective XCD chunk (m204) + gm=8 group walk
    const int nbx = gridDim.x, nby = gridDim.y;
    const int nwg = nbx * nby;
    int id = blockIdx.y * nbx + blockIdx.x;
    {
        const int q = nwg >> 3, r = nwg & 7;
        const int xcd = id & 7, off = id >> 3;
        id = (xcd < r) ? (xcd * (q + 1) + off) : (r * (q + 1) + (xcd - r) * q + off);
    }
    const int gm = 8;
    const int gidx = id / (gm * nbx);
    const int rem  = id - gidx * gm * nbx;
    const int width = min(gm, nby - gidx * gm);
    const int bm = (gidx * gm + rem % width) * BM;
    const int bn = (rem / width) * BN;

    const int tid  = threadIdx.x;
    const int wave = tid >> 6, lane = tid & 63;
    const int wm = wave >> 2, wn = wave & 3;
    const int lr = lane & 15, lq = lane >> 4;
    const int KT = K >> 5;

    // per-thread LDS read offsets (shorts), swizzled: key(row) = (row^(row>>2))&3
    int aoff[MF], boff[NI];
#pragma unroll
    for (int mf = 0; mf < MF; ++mf) {
        int row = wm * (BM / 2) + mf * 16 + lr;
        aoff[mf] = row * 32 + ((lq ^ ((row ^ (row >> 2)) & 3)) << 3);
    }
#pragma unroll
    for (int ni = 0; ni < NI; ++ni) {
        int row = wn * (BN / 4) + ni * 16 + lr;
        boff[ni] = ASH + row * 32 + ((lq ^ ((row ^ (row >> 2)) & 3)) << 3);
    }

    // staging lambdas: linear LDS dest, inverse-swizzled global source (rule #21)
    auto stageA = [&](int ktt, int sbuf, int q) {
        int _r = q * 128 + (tid >> 2);
        const unsigned short* src = A + (size_t)(bm + _r) * K + (ktt << 5)
                                      + (((tid & 3) ^ ((_r ^ (_r >> 2)) & 3)) << 3);
        GLD16(src, &lds[sbuf * BUF + q * 4096 + ((tid >> 6) << 9)]);
    };
    auto stageB = [&](int ktt, int sbuf, int q) {
        int _r = q * 128 + (tid >> 2);
        const unsigned short* src = BT + (size_t)(bn + _r) * K + (ktt << 5)
                                      + (((tid & 3) ^ ((_r ^ (_r >> 2)) & 3)) << 3);
        GLD16(src, &lds[sbuf * BUF + ASH + q * 4096 + ((tid >> 6) << 9)]);
    };

    f32x4 acc[MF][NI];
#pragma unroll
    for (int i = 0; i < MF; ++i)
#pragma unroll
        for (int j = 0; j < NI; ++j) acc[i][j] = (f32x4){0.f, 0.f, 0.f, 0.f};

    // ---- prologue: stage tiles 0,1; wait tile 0 ----
    {
#pragma unroll
        for (int q = 0; q < GA; ++q) stageA(0, 0, q);
#pragma unroll
        for (int q = 0; q < GB; ++q) stageB(0, 0, q);
#pragma unroll
        for (int q = 0; q < GA; ++q) stageA(1, 1, q);
#pragma unroll
        for (int q = 0; q < GB; ++q) stageB(1, 1, q);
        if constexpr (GT == 4)      { asm volatile("s_waitcnt vmcnt(4)" ::: "memory"); }
        else if constexpr (GT == 3) { asm volatile("s_waitcnt vmcnt(3)" ::: "memory"); }
        else                        { asm volatile("s_waitcnt vmcnt(2)" ::: "memory"); }
        __builtin_amdgcn_sched_barrier(0);
        __builtin_amdgcn_s_barrier();
        __builtin_amdgcn_sched_barrier(0);
    }

    int cur = 0, stg = 2;
    for (int kt = 0; kt < KT; ++kt) {
        const int cb = cur * BUF;
        const bool dostage = (kt + 2) < KT;
        bf16x8 af[MF], b0, b1;

        if constexpr (NI == 4) {
            // ---- phase alpha: A-frags + B ni0,1; stage A of tile kt+2 ----
#pragma unroll
            for (int mf = 0; mf < MF; ++mf) af[mf] = *(const bf16x8*)&lds[cb + aoff[mf]];
            b0 = *(const bf16x8*)&lds[cb + boff[0]];
            b1 = *(const bf16x8*)&lds[cb + boff[1]];
            if (dostage) { stageA(kt + 2, stg, 0); stageA(kt + 2, stg, 1); }
            BAR_WAIT;
            __builtin_amdgcn_s_setprio(1);
#pragma unroll
            for (int mf = 0; mf < MF; ++mf) {
                acc[mf][0] = __builtin_amdgcn_mfma_f32_16x16x32_bf16(af[mf], b0, acc[mf][0], 0, 0, 0);
                acc[mf][1] = __builtin_amdgcn_mfma_f32_16x16x32_bf16(af[mf], b1, acc[mf][1], 0, 0, 0);
            }
            __builtin_amdgcn_s_setprio(0);
            ENDBAR;
            // ---- phase beta: B ni2,3 (A reused); stage B of tile kt+2 ----
            b0 = *(const bf16x8*)&lds[cb + boff[2]];
            b1 = *(const bf16x8*)&lds[cb + boff[3]];
            if (dostage) { stageB(kt + 2, stg, 0); stageB(kt + 2, stg, 1); }
            BAR_WAIT;
            __builtin_amdgcn_s_setprio(1);
#pragma unroll
            for (int mf = 0; mf < MF; ++mf) {
                acc[mf][2] = __builtin_amdgcn_mfma_f32_16x16x32_bf16(af[mf], b0, acc[mf][2], 0, 0, 0);
                acc[mf][3] = __builtin_amdgcn_mfma_f32_16x16x32_bf16(af[mf], b1, acc[mf][3], 0, 0, 0);
            }
            __builtin_amdgcn_s_setprio(0);
            if (dostage) { asm volatile("s_waitcnt vmcnt(4)" ::: "memory"); }
            else         { asm volatile("s_waitcnt vmcnt(0)" ::: "memory"); }
            __builtin_amdgcn_sched_barrier(0);
            ENDBAR;
        } else {
            // ---- single phase: A-frags + both B frags; stage whole tile kt+2 ----
#pragma unroll
            for (int mf = 0; mf < MF; ++mf) af[mf] = *(const bf16x8*)&lds[cb + aoff[mf]];
            b0 = *(const bf16x8*)&lds[cb + boff[0]];
            b1 = *(const bf16x8*)&lds[cb + boff[1]];
            if (dostage) {
#pragma unroll
                for (int q = 0; q < GA; ++q) stageA(kt + 2, stg, q);
#pragma unroll
                for (int q = 0; q < GB; ++q) stageB(kt + 2, stg, q);
            }
            BAR_WAIT;
            __builtin_amdgcn_s_setprio(1);
#pragma unroll
            for (int mf = 0; mf < MF; ++mf) {
                acc[mf][0] = __builtin_amdgcn_mfma_f32_16x16x32_bf16(af[mf], b0, acc[mf][0], 0, 0, 0);
                acc[mf][1] = __builtin_amdgcn_mfma_f32_16x16x32_bf16(af[mf], b1, acc[mf][1], 0, 0, 0);
            }
            __builtin_amdgcn_s_setprio(0);
            if (dostage) {
                if constexpr (GT == 3) { asm volatile("s_waitcnt vmcnt(3)" ::: "memory"); }
                else                   { asm volatile("s_waitcnt vmcnt(2)" ::: "memory"); }
            } else                     { asm volatile("s_waitcnt vmcnt(0)" ::: "memory"); }
            __builtin_amdgcn_sched_barrier(0);
            ENDBAR;
        }

        cur = (cur == 2) ? 0 : cur + 1;
        stg = (stg == 2) ? 0 : stg + 1;
    }

    // ---- epilogue ----
#pragma unroll
    for (int mf = 0; mf < MF; ++mf)
#pragma unroll
        for (int ni = 0; ni < NI; ++ni)
#pragma unroll
            for (int r = 0; r < 4; ++r) {
                int grow = bm + wm * (BM / 2) + mf * 16 + lq * 4 + r;
                int gcol = bn + wn * (BN / 4) + ni * 16 + lr;
                float v = acc[mf][ni][r];
                if (EPI == 1) {
                    if (gcol < Ntot)
                        ((unsigned short*)Cout)[(size_t)grow * ldc + coff + gcol] = f2b(v);
                } else {
                    size_t idx = (size_t)grow * ldc + gcol;
                    ((float*)Cout)[idx] = ex[idx] + v * esc[gcol];
                }
            }
}

// ---------------- depthwise conv: sliding-window, each input read once ----------------
#define TCV 64
__global__ __launch_bounds__(256) void conv_kernel(
    const unsigned short* __restrict__ ZX,   // [4096][8320] bf16
    const float* __restrict__ cwF, const float* __restrict__ cbF,
    const float* __restrict__ cwB, const float* __restrict__ cbB,
    unsigned short* __restrict__ xs,         // [2][4096][2048] bf16
    float* __restrict__ Bc, float* __restrict__ Cc)  // [(d*2+b)*L+t][16]
{
    const int c = blockIdx.x * 256 + threadIdx.x;
    if (c >= CDIM) return;
    const int t0 = blockIdx.y * TCV;
    const int db = blockIdx.z;
    const int d = db >> 1, b = db & 1;
    const float* cw = d ? cwB : cwF;
    const float* cb = d ? cbB : cbF;
    float4 w = *(const float4*)&cw[c * 4];
    const float bias = cb[c];
    const unsigned short* base = ZX + (size_t)d * DIP + DI + c;  // + row*NW

    auto ldg = [&](int t) -> float {
        return (t >= 0 && t < LSEQ) ? b2f(base[(size_t)(b * LSEQ + t) * NW]) : 0.f;
    };
    auto emit = [&](int t, float acc) {
        float v = silu_f(acc);
        const int row = b * LSEQ + t;
        if (c < DI) {
            xs[((size_t)d * RTOT + row) * DI + c] = f2b(v);
        } else if (c < DI + NSTATE) {
            Bc[((size_t)db * LSEQ + t) * NSTATE + (c - DI)] = v;
        } else {
            Cc[((size_t)db * LSEQ + t) * NSTATE + (c - DI - NSTATE)] = v;
        }
    };

    if (d == 0) {
        float v0 = ldg(t0 - 3), v1 = ldg(t0 - 2), v2 = ldg(t0 - 1), vt = ldg(t0);
#pragma unroll 4
        for (int i = 0; i < TCV; ++i) {
            float vn = (i < TCV - 1) ? ldg(t0 + i + 1) : 0.f;
            emit(t0 + i, bias + w.x * v0 + w.y * v1 + w.z * v2 + w.w * vt);
            v0 = v1; v1 = v2; v2 = vt; vt = vn;
        }
    } else {
        float v3 = ldg(t0 + TCV + 2), v2 = ldg(t0 + TCV + 1), v1 = ldg(t0 + TCV), vt = ldg(t0 + TCV - 1);
#pragma unroll 4
        for (int i = TCV - 1; i >= 0; --i) {
            float vn = (i > 0) ? ldg(t0 + i - 1) : 0.f;
            emit(t0 + i, bias + w.w * vt + w.z * v1 + w.y * v2 + w.x * v3);
            v3 = v2; v2 = v1; v1 = vt; vt = vn;
        }
    }
}

// ---------------- dt: softplus + dA ----------------
__global__ __launch_bounds__(256) void dt_kernel(
    const unsigned short* __restrict__ ZX,
    const float* __restrict__ biasF, const float* __restrict__ AlogF,
    const float* __restrict__ biasB, const float* __restrict__ AlogB,
    float* __restrict__ dtb, float* __restrict__ dAb)
{
    int i = blockIdx.x * 256 + threadIdx.x;          // [d][b][t][h]
    int h = i & 31, t = (i >> 5) & 2047, b = (i >> 16) & 1, d = (i >> 17) & 1;
    float raw = b2f(ZX[(size_t)(b * LSEQ + t) * NW + d * DIP + (DI + CDIM) + h]);
    float bias = (d ? biasB : biasF)[h];
    float Alog = (d ? AlogB : AlogF)[h];
    float xv = raw + bias;
    float dt = (xv > 20.f) ? xv : __logf(1.f + __expf(xv));
    float A = -__expf(Alog);
    dtb[i] = dt;
    dAb[i] = __expf(dt * A);
}

#define LD16V(dst, ptr) do { const float4* _p = (const float4*)(ptr); \
    float4 _q0 = _p[0], _q1 = _p[1], _q2 = _p[2], _q3 = _p[3]; \
    dst[0]=_q0.x; dst[1]=_q0.y; dst[2]=_q0.z; dst[3]=_q0.w; \
    dst[4]=_q1.x; dst[5]=_q1.y; dst[6]=_q1.z; dst[7]=_q1.w; \
    dst[8]=_q2.x; dst[9]=_q2.y; dst[10]=_q2.z; dst[11]=_q2.w; \
    dst[12]=_q3.x; dst[13]=_q3.y; dst[14]=_q3.z; dst[15]=_q3.w; } while (0)

#define ST16V(ptr, src) do { float4* _p = (float4*)(ptr); \
    _p[0] = make_float4(src[0],src[1],src[2],src[3]); \
    _p[1] = make_float4(src[4],src[5],src[6],src[7]); \
    _p[2] = make_float4(src[8],src[9],src[10],src[11]); \
    _p[3] = make_float4(src[12],src[13],src[14],src[15]); } while (0)

// ---------------- pass A: per-chunk zero-init state + decay product ----------------
__global__ __launch_bounds__(64) void chunk_state_kernel(
    const unsigned short* __restrict__ xs,
    const float* __restrict__ Bc,
    const float* __restrict__ dtb, const float* __restrict__ dAb,
    float* __restrict__ Sbuf,               // [128][NCH][64][16]
    float* __restrict__ Pbuf)               // [128][NCH]
{
    const int h = blockIdx.x, db = blockIdx.y, c = blockIdx.z;
    const int d = db >> 1, b = db & 1;
    const int lane = threadIdx.x;
    float hs[16];
#pragma unroll
    for (int n = 0; n < 16; ++n) hs[n] = 0.f;
    float pacc = 1.f;
    const size_t dbase = (size_t)d * RTOT;
    const int s0 = c * QCH;

    float Bs[16], xv, dtv, dAv;
    float Bn[16], xn, dtn, dAn;
    {
        const int t = d ? (LSEQ - 1 - s0) : s0;
        const size_t row = (size_t)b * LSEQ + t, rdb = (size_t)db * LSEQ + t;
        xv  = b2f(xs[(dbase + row) * DI + h * HP + lane]);
        dtv = dtb[rdb * 32 + h]; dAv = dAb[rdb * 32 + h];
        LD16V(Bs, Bc + rdb * 16);
    }
#pragma unroll 2
    for (int i = 0; i < QCH; ++i) {
        const int sn = s0 + ((i < QCH - 1) ? i + 1 : i);
        const int tn = d ? (LSEQ - 1 - sn) : sn;
        {
            const size_t rown = (size_t)b * LSEQ + tn, rdbn = (size_t)db * LSEQ + tn;
            xn  = b2f(xs[(dbase + rown) * DI + h * HP + lane]);
            dtn = dtb[rdbn * 32 + h]; dAn = dAb[rdbn * 32 + h];
            LD16V(Bn, Bc + rdbn * 16);
        }
        const float dtx = dtv * xv;
#pragma unroll
        for (int n = 0; n < 16; ++n) hs[n] = fmaf(hs[n], dAv, Bs[n] * dtx);
        pacc *= dAv;
        xv = xn; dtv = dtn; dAv = dAn;
#pragma unroll
        for (int n = 0; n < 16; ++n) Bs[n] = Bn[n];
    }
    float* Sp = Sbuf + (((size_t)(db * NH + h)) * NCH + c) * 1024 + lane * 16;
    ST16V(Sp, hs);
    if (lane == 0) Pbuf[(db * NH + h) * NCH + c] = pacc;
}

// ---------------- pass B: sequential combine over chunks (tiny) ----------------
__global__ __launch_bounds__(64) void chunk_combine_kernel(
    const float* __restrict__ Sbuf, const float* __restrict__ Pbuf,
    float* __restrict__ Hbuf)               // [128][NCH][64][16]
{
    const int idx = blockIdx.x;
    const int lane = threadIdx.x;
    float hs[16];
#pragma unroll
    for (int n = 0; n < 16; ++n) hs[n] = 0.f;
    float* H0 = Hbuf + ((size_t)idx * NCH) * 1024 + lane * 16;
    ST16V(H0, hs);
    for (int c = 0; c < NCH - 1; ++c) {
        const float* Sp = Sbuf + ((size_t)idx * NCH + c) * 1024 + lane * 16;
        float S[16];
        LD16V(S, Sp);
        const float P = Pbuf[idx * NCH + c];
#pragma unroll
        for (int n = 0; n < 16; ++n) hs[n] = fmaf(hs[n], P, S[n]);
        float* Hp = Hbuf + ((size_t)idx * NCH + c + 1) * 1024 + lane * 16;
        ST16V(Hp, hs);
    }
}

// ---------------- pass C: per-chunk scan from Hinit, emit y ----------------
__global__ __launch_bounds__(64) void chunk_scan_kernel(
    const unsigned short* __restrict__ xs,
    const float* __restrict__ Bc, const float* __restrict__ Cc,
    const float* __restrict__ dtb, const float* __restrict__ dAb,
    const float* __restrict__ DpF, const float* __restrict__ DpB,
    const float* __restrict__ Hbuf,
    unsigned short* __restrict__ ybuf)       // [2][4096][2048]
{
    const int h = blockIdx.x, db = blockIdx.y, c = blockIdx.z;
    const int d = db >> 1, b = db & 1;
    const int lane = threadIdx.x;
    const float Dp = (d ? DpB : DpF)[h];
    float hs[16];
    {
        const float* Hp = Hbuf + ((size_t)(db * NH + h) * NCH + c) * 1024 + lane * 16;
        LD16V(hs, Hp);
    }
    const size_t dbase = (size_t)d * RTOT;
    const int s0 = c * QCH;

    float Bs[16], Cs[16], xv, dtv, dAv;
    float Bn[16], Cn[16], xn, dtn, dAn;
    {
        const int t = d ? (LSEQ - 1 - s0) : s0;
        const size_t row = (size_t)b * LSEQ + t, rdb = (size_t)db * LSEQ + t;
        xv  = b2f(xs[(dbase + row) * DI + h * HP + lane]);
        dtv = dtb[rdb * 32 + h]; dAv = dAb[rdb * 32 + h];
        LD16V(Bs, Bc + rdb * 16);
        LD16V(Cs, Cc + rdb * 16);
    }
#pragma unroll 2
    for (int i = 0; i < QCH; ++i) {
        const int sn = s0 + ((i < QCH - 1) ? i + 1 : i);
        const int tn = d ? (LSEQ - 1 - sn) : sn;
        {
            const size_t rown = (size_t)b * LSEQ + tn, rdbn = (size_t)db * LSEQ + tn;
            xn  = b2f(xs[(dbase + rown) * DI + h * HP + lane]);
            dtn = dtb[rdbn * 32 + h]; dAn = dAb[rdbn * 32 + h];
            LD16V(Bn, Bc + rdbn * 16);
            LD16V(Cn, Cc + rdbn * 16);
        }
        const float dtx = dtv * xv;
        float yq[4] = {0.f, 0.f, 0.f, 0.f};
#pragma unroll
        for (int n = 0; n < 16; ++n) {
            hs[n] = fmaf(hs[n], dAv, Bs[n] * dtx);
            yq[n & 3] = fmaf(Cs[n], hs[n], yq[n & 3]);
        }
        const int t = d ? (LSEQ - 1 - (s0 + i)) : (s0 + i);
        const size_t row = (size_t)b * LSEQ + t;
        ybuf[(dbase + row) * DI + h * HP + lane] = f2b(((yq[0] + yq[1]) + (yq[2] + yq[3])) + Dp * xv);

        xv = xn; dtv = dtn; dAv = dAn;
#pragma unroll
        for (int n = 0; n < 16; ++n) { Bs[n] = Bn[n]; Cs[n] = Cn[n]; }
    }
}

// ---------------- gate (silu(z)) + RMSNorm -> bf16 ----------------
__global__ __launch_bounds__(256) void gatenorm_kernel(
    const unsigned short* __restrict__ ybuf, const unsigned short* __restrict__ ZX,
    const float* __restrict__ nwF, const float* __restrict__ nwB,
    unsigned short* __restrict__ yg)
{
    const int r = blockIdx.x;      // 0..4095 (b*L+t)
    const int d = blockIdx.y;
    const int tid = threadIdx.x;
    const float* nw = d ? nwB : nwF;
    const int c0 = tid * 8;
    const unsigned short* yp = ybuf + ((size_t)d * RTOT + r) * DI + c0;
    const unsigned short* zp = ZX + (size_t)r * NW + d * DIP + c0;
    uint4 yv = *(const uint4*)yp;
    uint4 zv = *(const uint4*)zp;
    unsigned int yw[4] = {yv.x, yv.y, yv.z, yv.w};
    unsigned int zw[4] = {zv.x, zv.y, zv.z, zv.w};
    float g[8]; float ss = 0.f;
#pragma unroll
    for (int i = 0; i < 8; ++i) {
        unsigned short yu = (i & 1) ? (unsigned short)(yw[i >> 1] >> 16) : (unsigned short)(yw[i >> 1] & 0xffff);
        unsigned short zu = (i & 1) ? (unsigned short)(zw[i >> 1] >> 16) : (unsigned short)(zw[i >> 1] & 0xffff);
        float y = b2f(yu), z = b2f(zu);
        float gv = y * silu_f(z);
        g[i] = gv; ss += gv * gv;
    }
#pragma unroll
    for (int m = 1; m < 64; m <<= 1) ss += __shfl_xor(ss, m, 64);
    __shared__ float red[4];
    if ((tid & 63) == 0) red[tid >> 6] = ss;
    __syncthreads();
    float tot = red[0] + red[1] + red[2] + red[3];
    float sc = rsqrtf(tot * (1.f / 2048.f) + 1e-5f);
    union { unsigned short s[8]; uint4 u; } o;
#pragma unroll
    for (int i = 0; i < 8; ++i) o.s[i] = f2b(g[i] * sc * nw[c0 + i]);
    *(uint4*)(yg + ((size_t)d * RTOT + r) * DI + c0) = o.u;
}

// ---------------- host ----------------
extern "C" void kernel_launch(void* const* d_in, const int* in_sizes, int n_in,
                              void* d_out, int out_size, void* d_ws, size_t ws_size,
                              hipStream_t stream)
{
    const float* x     = (const float*)d_in[0];
    const float* fin   = (const float*)d_in[1];
    const float* fcw   = (const float*)d_in[2];
    const float* fcb   = (const float*)d_in[3];
    const float* fdtb  = (const float*)d_in[4];
    const float* fAlog = (const float*)d_in[5];
    const float* fDp   = (const float*)d_in[6];
    const float* fnw   = (const float*)d_in[7];
    const float* fout  = (const float*)d_in[8];
    const float* bin   = (const float*)d_in[9];
    const float* bcw   = (const float*)d_in[10];
    const float* bcb   = (const float*)d_in[11];
    const float* bdtb  = (const float*)d_in[12];
    const float* bAlog = (const float*)d_in[13];
    const float* bDp   = (const float*)d_in[14];
    const float* bnw   = (const float*)d_in[15];
    const float* bout  = (const float*)d_in[16];
    const float* lw    = (const float*)d_in[17];
    const float* lsc   = (const float*)d_in[18];

    char* w = (char*)d_ws;
    auto alloc = [&](size_t bytes) { char* p = w; w += (bytes + 255) & ~(size_t)255; return p; };
    unsigned short* xb  = (unsigned short*)alloc((size_t)RTOT * DM * 2);
    // win padded to 8448 rows so GEMM A's last 256-col block reads in-bounds
    unsigned short* win = (unsigned short*)alloc((size_t)(NW + 128) * DM * 2);
    unsigned short* wo  = (unsigned short*)alloc((size_t)2 * DM * DI * 2);
    unsigned short* wl  = (unsigned short*)alloc((size_t)DM * DI * 2);
    unsigned short* zx  = (unsigned short*)alloc((size_t)RTOT * NW * 2);
    unsigned short* xs  = (unsigned short*)alloc((size_t)2 * RTOT * DI * 2);
    float* Bc  = (float*)alloc((size_t)2 * RTOT * NSTATE * 4);
    float* Cc  = (float*)alloc((size_t)2 * RTOT * NSTATE * 4);
    float* dtb = (float*)alloc((size_t)2 * RTOT * NH * 4);
    float* dAb = (float*)alloc((size_t)2 * RTOT * NH * 4);
    unsigned short* yb  = (unsigned short*)alloc((size_t)2 * RTOT * DI * 2);
    unsigned short* yg  = (unsigned short*)alloc((size_t)2 * RTOT * DI * 2);
    unsigned short* hbi = (unsigned short*)alloc((size_t)RTOT * DI * 2);
    float* Pbuf = (float*)alloc((size_t)128 * NCH * 4);
    // Sbuf/Hbuf alias xb and win (dead after GEMM A).
    float* Sbuf = (float*)xb;
    float* Hbuf = (float*)win;
    (void)ws_size; (void)in_sizes; (void)n_in; (void)out_size;

    // batched weight/activation converts to bf16 (one dispatch)
    CvtJobs jobs;
    jobs.src[0] = x;    jobs.dst[0] = xb;                        jobs.n4[0] = RTOT * DM / 4;
    jobs.src[1] = fin;  jobs.dst[1] = win;                       jobs.n4[1] = DIP * DM / 4;
    jobs.src[2] = bin;  jobs.dst[2] = win + (size_t)DIP * DM;    jobs.n4[2] = DIP * DM / 4;
    jobs.src[3] = fout; jobs.dst[3] = wo;                        jobs.n4[3] = DM * DI / 4;
    jobs.src[4] = bout; jobs.dst[4] = wo + (size_t)DM * DI;      jobs.n4[4] = DM * DI / 4;
    jobs.src[5] = lw;   jobs.dst[5] = wl;                        jobs.n4[5] = DM * DI / 4;
    cvtb_kernel<<<dim3((DIP * DM / 4 + 255) / 256, 6), 256, 0, stream>>>(jobs);

    // GEMM A: zxbcdt both dirs (stacked weights). M=4096, N=8320 (pad->8448), K=1024
    gemmX_kernel<256, 256, 1><<<dim3(33, RTOT / 256), 512, 0, stream>>>(
        xb, win, nullptr, nullptr, zx, NW, DM, NW, 0, 0, nullptr, nullptr);

    // conv + silu + split (fwd causal, bwd anti-causal), sliding-window
    conv_kernel<<<dim3((CDIM + 255) / 256, LSEQ / TCV, 4), 256, 0, stream>>>(
        zx, fcw, fcb, bcw, bcb, xs, Bc, Cc);

    // dt softplus + dA
    dt_kernel<<<(2 * NB * LSEQ * NH) / 256, 256, 0, stream>>>(
        zx, fdtb, fAlog, bdtb, bAlog, dtb, dAb);

    // chunked scan: A) per-chunk states, B) combine, C) per-chunk scan+y
    chunk_state_kernel<<<dim3(NH, 4, NCH - 1), 64, 0, stream>>>(
        xs, Bc, dtb, dAb, Sbuf, Pbuf);
    chunk_combine_kernel<<<128, 64, 0, stream>>>(Sbuf, Pbuf, Hbuf);
    chunk_scan_kernel<<<dim3(NH, 4, NCH), 64, 0, stream>>>(
        xs, Bc, Cc, dtb, dAb, fDp, bDp, Hbuf, yb);

    // gate + RMSNorm
    gatenorm_kernel<<<dim3(RTOT, 2), 256, 0, stream>>>(yb, zx, fnw, bnw, yg);

    // GEMM B: out_proj both dirs fused (grid.z=2). M=4096, N=1024, K=2048
    gemmX_kernel<256, 128, 1><<<dim3(DM / 128, RTOT / 256, 2), 512, 0, stream>>>(
        yg, wo, yg + (size_t)RTOT * DI, wo + (size_t)DM * DI,
        hbi, DM, DI, DI, 0, DM, nullptr, nullptr);

    // GEMM C: layer out proj + residual epilogue. M=4096, N=1024, K=2048
    gemmX_kernel<128, 128, 2><<<dim3(DM / 128, RTOT / 128), 512, 0, stream>>>(
        hbi, wl, nullptr, nullptr, d_out, DM, DI, DM, 0, 0, x, lsc);
}

// Round 6
// 364.196 us; speedup vs baseline: 1.0552x; 1.0552x over previous
//
#include <hip/hip_runtime.h>

// ---------------- helpers ----------------
typedef __attribute__((ext_vector_type(8))) short bf16x8;   // 8 bf16 (4 VGPRs)
typedef __attribute__((ext_vector_type(4))) float f32x4;

#define DEV static __device__ __forceinline__

DEV float b2f(unsigned short u) {
    union { unsigned int u; float f; } c; c.u = ((unsigned int)u) << 16; return c.f;
}
DEV unsigned short f2b(float f) {
    union { float f; unsigned int u; } c; c.f = f;
    unsigned int u = c.u + 0x7fffu + ((c.u >> 16) & 1u);
    return (unsigned short)(u >> 16);
}
DEV float silu_f(float v) { return v / (1.f + __expf(-v)); }

#define GLD16(gp, lp) __builtin_amdgcn_global_load_lds( \
    (const __attribute__((address_space(1))) void*)(gp), \
    (__attribute__((address_space(3))) void*)(lp), 16, 0, 0)

// sizes
#define LSEQ 2048
#define NB 2
#define RTOT 4096          // NB*LSEQ
#define DM 1024
#define DI 2048
#define NH 32
#define HP 64
#define NSTATE 16
#define CDIM 2080
#define DIP 4160           // per-dir in_proj width
#define NW 8320            // stacked width
#define QCH 128            // scan chunk length
#define NCH (LSEQ / QCH)   // 16 chunks

// ---------------- batched f32 -> bf16 convert ----------------
struct CvtJobs {
    const float* src[6];
    unsigned short* dst[6];
    int n4[6];
};
__global__ __launch_bounds__(256) void cvtb_kernel(CvtJobs j) {
    const int jb = blockIdx.y;
    const int i = blockIdx.x * 256 + threadIdx.x;
    if (i >= j.n4[jb]) return;
    float4 v = ((const float4*)j.src[jb])[i];
    union { unsigned short s[4]; uint2 u; } p;
    p.s[0] = f2b(v.x); p.s[1] = f2b(v.y); p.s[2] = f2b(v.z); p.s[3] = f2b(v.w);
    ((uint2*)j.dst[jb])[i] = p.u;
}

// ---------------- pipelined bf16 MFMA GEMM, decoupled single-barrier schedule ----------------
// BK=32, 8 waves (2M x 4N), 3 LDS tile-buffers, stage t+2 while computing t.
// Per K-tile: issue gloads(t+2); plain ds_reads (compiler-counted lgkm); MFMA;
// counted vmcnt(GT); ONE s_barrier. Reads/MFMAs of different waves overlap freely.
// A: M x K row-major; BT: N x K row-major. EPI 1 = bf16 store (clamped at Ntot);
// EPI 2 = f32 ex + v*esc. grid.z selects (A,BT,coff) for fused dual-GEMM.

template<int BM, int BN, int EPI>
__global__ void __launch_bounds__(512, 4)
gemmP_kernel(
    const unsigned short* __restrict__ A0, const unsigned short* __restrict__ BT0,
    const unsigned short* __restrict__ A1, const unsigned short* __restrict__ BT1,
    void* __restrict__ Cout,
    int Ntot, int K, int ldc, int coff0, int coff1,
    const float* __restrict__ ex, const float* __restrict__ esc)
{
    constexpr int MF = BM / 32;            // per-wave m-frags (2 M-waves)
    constexpr int NI = BN / 64;            // per-wave n-frags (4 N-waves)
    constexpr int GA = BM / 128, GB = BN / 128;
    constexpr int GT = GA + GB;            // gloads per tile per thread
    constexpr int ASH = BM * 32;           // shorts per A K32-tile
    constexpr int BSH = BN * 32;
    constexpr int BUFS = ASH + BSH;
    __shared__ unsigned short lds[3 * BUFS];

    const unsigned short* __restrict__ A  = blockIdx.z ? A1 : A0;
    const unsigned short* __restrict__ BT = blockIdx.z ? BT1 : BT0;
    const int coff = blockIdx.z ? coff1 : coff0;

    // bijective XCD chunk (m204) + gm=8 group walk
    const int nbx = gridDim.x, nby = gridDim.y;
    const int nwg = nbx * nby;
    int id = blockIdx.y * nbx + blockIdx.x;
    {
        const int q = nwg >> 3, r = nwg & 7;
        const int xcd = id & 7, off = id >> 3;
        id = (xcd < r) ? (xcd * (q + 1) + off) : (r * (q + 1) + (xcd - r) * q + off);
    }
    const int gm = 8;
    const int gidx = id / (gm * nbx);
    const int rem  = id - gidx * gm * nbx;
    const int width = min(gm, nby - gidx * gm);
    const int bm = (gidx * gm + rem % width) * BM;
    const int bn = (rem / width) * BN;

    const int tid  = threadIdx.x;
    const int wave = tid >> 6, lane = tid & 63;
    const int wm = wave >> 2, wn = wave & 3;
    const int lr = lane & 15, lq = lane >> 4;
    const int KT = K >> 5;

    // per-thread LDS read offsets (shorts), swizzle key(row) = (row^(row>>2))&3
    int aoff[MF], boff[NI];
#pragma unroll
    for (int mf = 0; mf < MF; ++mf) {
        int row = wm * (BM / 2) + mf * 16 + lr;
        aoff[mf] = row * 32 + ((lq ^ ((row ^ (row >> 2)) & 3)) << 3);
    }
#pragma unroll
    for (int ni = 0; ni < NI; ++ni) {
        int row = wn * (BN / 4) + ni * 16 + lr;
        boff[ni] = ASH + row * 32 + ((lq ^ ((row ^ (row >> 2)) & 3)) << 3);
    }

    // staging: linear LDS dest, inverse-swizzled global source (rule #21)
    auto stageA = [&](int ktt, int sbuf) {
#pragma unroll
        for (int q = 0; q < GA; ++q) {
            int _r = q * 128 + (tid >> 2);
            const unsigned short* src = A + (size_t)(bm + _r) * K + (ktt << 5)
                                          + (((tid & 3) ^ ((_r ^ (_r >> 2)) & 3)) << 3);
            GLD16(src, &lds[sbuf * BUFS + q * 4096 + ((tid >> 6) << 9)]);
        }
    };
    auto stageB = [&](int ktt, int sbuf) {
#pragma unroll
        for (int q = 0; q < GB; ++q) {
            int _r = q * 128 + (tid >> 2);
            const unsigned short* src = BT + (size_t)(bn + _r) * K + (ktt << 5)
                                          + (((tid & 3) ^ ((_r ^ (_r >> 2)) & 3)) << 3);
            GLD16(src, &lds[sbuf * BUFS + ASH + q * 4096 + ((tid >> 6) << 9)]);
        }
    };

    f32x4 acc[MF][NI];
#pragma unroll
    for (int i = 0; i < MF; ++i)
#pragma unroll
        for (int j = 0; j < NI; ++j) acc[i][j] = (f32x4){0.f, 0.f, 0.f, 0.f};

    // ---- prologue: stage tiles 0,1; own-vmcnt + barrier -> buf0 valid for all ----
    stageA(0, 0); stageB(0, 0);
    if (KT > 1) { stageA(1, 1); stageB(1, 1); }
    if constexpr (GT == 3) { asm volatile("s_waitcnt vmcnt(3)" ::: "memory"); }
    else                   { asm volatile("s_waitcnt vmcnt(2)" ::: "memory"); }
    __builtin_amdgcn_sched_barrier(0);
    __builtin_amdgcn_s_barrier();
    __builtin_amdgcn_sched_barrier(0);

    int cur = 0, stg = 2;
    for (int kt = 0; kt < KT; ++kt) {
        const int cb = cur * BUFS;
        const bool dostage = (kt + 2) < KT;

        // issue long-latency staging first (lands >= 2 tiles later)
        if (dostage) { stageA(kt + 2, stg); stageB(kt + 2, stg); }

        // plain LDS reads + MFMA: compiler inserts fine-grained lgkm waits,
        // waves stagger freely (no barrier between reads and MFMA).
        bf16x8 af[MF], bf[NI];
#pragma unroll
        for (int mf = 0; mf < MF; ++mf) af[mf] = *(const bf16x8*)&lds[cb + aoff[mf]];
#pragma unroll
        for (int ni = 0; ni < NI; ++ni) bf[ni] = *(const bf16x8*)&lds[cb + boff[ni]];

        __builtin_amdgcn_s_setprio(1);
#pragma unroll
        for (int mf = 0; mf < MF; ++mf)
#pragma unroll
            for (int ni = 0; ni < NI; ++ni)
                acc[mf][ni] = __builtin_amdgcn_mfma_f32_16x16x32_bf16(af[mf], bf[ni], acc[mf][ni], 0, 0, 0);
        __builtin_amdgcn_s_setprio(0);

        // counted vmcnt: batch issued at kt-1 (for tile kt+1) must be complete.
        if (dostage) {
            if constexpr (GT == 3) { asm volatile("s_waitcnt vmcnt(3)" ::: "memory"); }
            else                   { asm volatile("s_waitcnt vmcnt(2)" ::: "memory"); }
        } else {
            asm volatile("s_waitcnt vmcnt(0)" ::: "memory");
        }
        __builtin_amdgcn_sched_barrier(0);
        __builtin_amdgcn_s_barrier();
        __builtin_amdgcn_sched_barrier(0);

        cur = (cur == 2) ? 0 : cur + 1;
        stg = (stg == 2) ? 0 : stg + 1;
    }

    // ---- epilogue ----
#pragma unroll
    for (int mf = 0; mf < MF; ++mf)
#pragma unroll
        for (int ni = 0; ni < NI; ++ni)
#pragma unroll
            for (int r = 0; r < 4; ++r) {
                int grow = bm + wm * (BM / 2) + mf * 16 + lq * 4 + r;
                int gcol = bn + wn * (BN / 4) + ni * 16 + lr;
                float v = acc[mf][ni][r];
                if (EPI == 1) {
                    if (gcol < Ntot)
                        ((unsigned short*)Cout)[(size_t)grow * ldc + coff + gcol] = f2b(v);
                } else {
                    size_t idx = (size_t)grow * ldc + gcol;
                    ((float*)Cout)[idx] = ex[idx] + v * esc[gcol];
                }
            }
}

// ---------------- depthwise conv: sliding-window, each input read once ----------------
#define TCV 64
__global__ __launch_bounds__(256) void conv_kernel(
    const unsigned short* __restrict__ ZX,   // [4096][8320] bf16
    const float* __restrict__ cwF, const float* __restrict__ cbF,
    const float* __restrict__ cwB, const float* __restrict__ cbB,
    unsigned short* __restrict__ xs,         // [2][4096][2048] bf16
    float* __restrict__ Bc, float* __restrict__ Cc)  // [(d*2+b)*L+t][16]
{
    const int c = blockIdx.x * 256 + threadIdx.x;
    if (c >= CDIM) return;
    const int t0 = blockIdx.y * TCV;
    const int db = blockIdx.z;
    const int d = db >> 1, b = db & 1;
    const float* cw = d ? cwB : cwF;
    const float* cb = d ? cbB : cbF;
    float4 w = *(const float4*)&cw[c * 4];
    const float bias = cb[c];
    const unsigned short* base = ZX + (size_t)d * DIP + DI + c;  // + row*NW

    auto ldg = [&](int t) -> float {
        return (t >= 0 && t < LSEQ) ? b2f(base[(size_t)(b * LSEQ + t) * NW]) : 0.f;
    };
    auto emit = [&](int t, float acc) {
        float v = silu_f(acc);
        const int row = b * LSEQ + t;
        if (c < DI) {
            xs[((size_t)d * RTOT + row) * DI + c] = f2b(v);
        } else if (c < DI + NSTATE) {
            Bc[((size_t)db * LSEQ + t) * NSTATE + (c - DI)] = v;
        } else {
            Cc[((size_t)db * LSEQ + t) * NSTATE + (c - DI - NSTATE)] = v;
        }
    };

    if (d == 0) {
        float v0 = ldg(t0 - 3), v1 = ldg(t0 - 2), v2 = ldg(t0 - 1), vt = ldg(t0);
#pragma unroll 4
        for (int i = 0; i < TCV; ++i) {
            float vn = (i < TCV - 1) ? ldg(t0 + i + 1) : 0.f;
            emit(t0 + i, bias + w.x * v0 + w.y * v1 + w.z * v2 + w.w * vt);
            v0 = v1; v1 = v2; v2 = vt; vt = vn;
        }
    } else {
        float v3 = ldg(t0 + TCV + 2), v2 = ldg(t0 + TCV + 1), v1 = ldg(t0 + TCV), vt = ldg(t0 + TCV - 1);
#pragma unroll 4
        for (int i = TCV - 1; i >= 0; --i) {
            float vn = (i > 0) ? ldg(t0 + i - 1) : 0.f;
            emit(t0 + i, bias + w.w * vt + w.z * v1 + w.y * v2 + w.x * v3);
            v3 = v2; v2 = v1; v1 = vt; vt = vn;
        }
    }
}

// ---------------- dt: softplus + dA ----------------
__global__ __launch_bounds__(256) void dt_kernel(
    const unsigned short* __restrict__ ZX,
    const float* __restrict__ biasF, const float* __restrict__ AlogF,
    const float* __restrict__ biasB, const float* __restrict__ AlogB,
    float* __restrict__ dtb, float* __restrict__ dAb)
{
    int i = blockIdx.x * 256 + threadIdx.x;          // [d][b][t][h]
    int h = i & 31, t = (i >> 5) & 2047, b = (i >> 16) & 1, d = (i >> 17) & 1;
    float raw = b2f(ZX[(size_t)(b * LSEQ + t) * NW + d * DIP + (DI + CDIM) + h]);
    float bias = (d ? biasB : biasF)[h];
    float Alog = (d ? AlogB : AlogF)[h];
    float xv = raw + bias;
    float dt = (xv > 20.f) ? xv : __logf(1.f + __expf(xv));
    float A = -__expf(Alog);
    dtb[i] = dt;
    dAb[i] = __expf(dt * A);
}

#define LD16V(dst, ptr) do { const float4* _p = (const float4*)(ptr); \
    float4 _q0 = _p[0], _q1 = _p[1], _q2 = _p[2], _q3 = _p[3]; \
    dst[0]=_q0.x; dst[1]=_q0.y; dst[2]=_q0.z; dst[3]=_q0.w; \
    dst[4]=_q1.x; dst[5]=_q1.y; dst[6]=_q1.z; dst[7]=_q1.w; \
    dst[8]=_q2.x; dst[9]=_q2.y; dst[10]=_q2.z; dst[11]=_q2.w; \
    dst[12]=_q3.x; dst[13]=_q3.y; dst[14]=_q3.z; dst[15]=_q3.w; } while (0)

#define ST16V(ptr, src) do { float4* _p = (float4*)(ptr); \
    _p[0] = make_float4(src[0],src[1],src[2],src[3]); \
    _p[1] = make_float4(src[4],src[5],src[6],src[7]); \
    _p[2] = make_float4(src[8],src[9],src[10],src[11]); \
    _p[3] = make_float4(src[12],src[13],src[14],src[15]); } while (0)

// ---------------- pass A: per-chunk zero-init state + decay product ----------------
__global__ __launch_bounds__(64) void chunk_state_kernel(
    const unsigned short* __restrict__ xs,
    const float* __restrict__ Bc,
    const float* __restrict__ dtb, const float* __restrict__ dAb,
    float* __restrict__ Sbuf,               // [128][NCH][64][16]
    float* __restrict__ Pbuf)               // [128][NCH]
{
    const int h = blockIdx.x, db = blockIdx.y, c = blockIdx.z;
    const int d = db >> 1, b = db & 1;
    const int lane = threadIdx.x;
    float hs[16];
#pragma unroll
    for (int n = 0; n < 16; ++n) hs[n] = 0.f;
    float pacc = 1.f;
    const size_t dbase = (size_t)d * RTOT;
    const int s0 = c * QCH;

    float Bs[16], xv, dtv, dAv;
    float Bn[16], xn, dtn, dAn;
    {
        const int t = d ? (LSEQ - 1 - s0) : s0;
        const size_t row = (size_t)b * LSEQ + t, rdb = (size_t)db * LSEQ + t;
        xv  = b2f(xs[(dbase + row) * DI + h * HP + lane]);
        dtv = dtb[rdb * 32 + h]; dAv = dAb[rdb * 32 + h];
        LD16V(Bs, Bc + rdb * 16);
    }
#pragma unroll 2
    for (int i = 0; i < QCH; ++i) {
        const int sn = s0 + ((i < QCH - 1) ? i + 1 : i);
        const int tn = d ? (LSEQ - 1 - sn) : sn;
        {
            const size_t rown = (size_t)b * LSEQ + tn, rdbn = (size_t)db * LSEQ + tn;
            xn  = b2f(xs[(dbase + rown) * DI + h * HP + lane]);
            dtn = dtb[rdbn * 32 + h]; dAn = dAb[rdbn * 32 + h];
            LD16V(Bn, Bc + rdbn * 16);
        }
        const float dtx = dtv * xv;
#pragma unroll
        for (int n = 0; n < 16; ++n) hs[n] = fmaf(hs[n], dAv, Bs[n] * dtx);
        pacc *= dAv;
        xv = xn; dtv = dtn; dAv = dAn;
#pragma unroll
        for (int n = 0; n < 16; ++n) Bs[n] = Bn[n];
    }
    float* Sp = Sbuf + (((size_t)(db * NH + h)) * NCH + c) * 1024 + lane * 16;
    ST16V(Sp, hs);
    if (lane == 0) Pbuf[(db * NH + h) * NCH + c] = pacc;
}

// ---------------- pass B: sequential combine over chunks (tiny) ----------------
__global__ __launch_bounds__(64) void chunk_combine_kernel(
    const float* __restrict__ Sbuf, const float* __restrict__ Pbuf,
    float* __restrict__ Hbuf)               // [128][NCH][64][16]
{
    const int idx = blockIdx.x;
    const int lane = threadIdx.x;
    float hs[16];
#pragma unroll
    for (int n = 0; n < 16; ++n) hs[n] = 0.f;
    float* H0 = Hbuf + ((size_t)idx * NCH) * 1024 + lane * 16;
    ST16V(H0, hs);
    for (int c = 0; c < NCH - 1; ++c) {
        const float* Sp = Sbuf + ((size_t)idx * NCH + c) * 1024 + lane * 16;
        float S[16];
        LD16V(S, Sp);
        const float P = Pbuf[idx * NCH + c];
#pragma unroll
        for (int n = 0; n < 16; ++n) hs[n] = fmaf(hs[n], P, S[n]);
        float* Hp = Hbuf + ((size_t)idx * NCH + c + 1) * 1024 + lane * 16;
        ST16V(Hp, hs);
    }
}

// ---------------- pass C: per-chunk scan from Hinit, emit y ----------------
__global__ __launch_bounds__(64) void chunk_scan_kernel(
    const unsigned short* __restrict__ xs,
    const float* __restrict__ Bc, const float* __restrict__ Cc,
    const float* __restrict__ dtb, const float* __restrict__ dAb,
    const float* __restrict__ DpF, const float* __restrict__ DpB,
    const float* __restrict__ Hbuf,
    unsigned short* __restrict__ ybuf)       // [2][4096][2048]
{
    const int h = blockIdx.x, db = blockIdx.y, c = blockIdx.z;
    const int d = db >> 1, b = db & 1;
    const int lane = threadIdx.x;
    const float Dp = (d ? DpB : DpF)[h];
    float hs[16];
    {
        const float* Hp = Hbuf + ((size_t)(db * NH + h) * NCH + c) * 1024 + lane * 16;
        LD16V(hs, Hp);
    }
    const size_t dbase = (size_t)d * RTOT;
    const int s0 = c * QCH;

    float Bs[16], Cs[16], xv, dtv, dAv;
    float Bn[16], Cn[16], xn, dtn, dAn;
    {
        const int t = d ? (LSEQ - 1 - s0) : s0;
        const size_t row = (size_t)b * LSEQ + t, rdb = (size_t)db * LSEQ + t;
        xv  = b2f(xs[(dbase + row) * DI + h * HP + lane]);
        dtv = dtb[rdb * 32 + h]; dAv = dAb[rdb * 32 + h];
        LD16V(Bs, Bc + rdb * 16);
        LD16V(Cs, Cc + rdb * 16);
    }
#pragma unroll 2
    for (int i = 0; i < QCH; ++i) {
        const int sn = s0 + ((i < QCH - 1) ? i + 1 : i);
        const int tn = d ? (LSEQ - 1 - sn) : sn;
        {
            const size_t rown = (size_t)b * LSEQ + tn, rdbn = (size_t)db * LSEQ + tn;
            xn  = b2f(xs[(dbase + rown) * DI + h * HP + lane]);
            dtn = dtb[rdbn * 32 + h]; dAn = dAb[rdbn * 32 + h];
            LD16V(Bn, Bc + rdbn * 16);
            LD16V(Cn, Cc + rdbn * 16);
        }
        const float dtx = dtv * xv;
        float yq[4] = {0.f, 0.f, 0.f, 0.f};
#pragma unroll
        for (int n = 0; n < 16; ++n) {
            hs[n] = fmaf(hs[n], dAv, Bs[n] * dtx);
            yq[n & 3] = fmaf(Cs[n], hs[n], yq[n & 3]);
        }
        const int t = d ? (LSEQ - 1 - (s0 + i)) : (s0 + i);
        const size_t row = (size_t)b * LSEQ + t;
        ybuf[(dbase + row) * DI + h * HP + lane] = f2b(((yq[0] + yq[1]) + (yq[2] + yq[3])) + Dp * xv);

        xv = xn; dtv = dtn; dAv = dAn;
#pragma unroll
        for (int n = 0; n < 16; ++n) { Bs[n] = Bn[n]; Cs[n] = Cn[n]; }
    }
}

// ---------------- gate (silu(z)) + RMSNorm -> bf16 ----------------
__global__ __launch_bounds__(256) void gatenorm_kernel(
    const unsigned short* __restrict__ ybuf, const unsigned short* __restrict__ ZX,
    const float* __restrict__ nwF, const float* __restrict__ nwB,
    unsigned short* __restrict__ yg)
{
    const int r = blockIdx.x;      // 0..4095 (b*L+t)
    const int d = blockIdx.y;
    const int tid = threadIdx.x;
    const float* nw = d ? nwB : nwF;
    const int c0 = tid * 8;
    const unsigned short* yp = ybuf + ((size_t)d * RTOT + r) * DI + c0;
    const unsigned short* zp = ZX + (size_t)r * NW + d * DIP + c0;
    uint4 yv = *(const uint4*)yp;
    uint4 zv = *(const uint4*)zp;
    unsigned int yw[4] = {yv.x, yv.y, yv.z, yv.w};
    unsigned int zw[4] = {zv.x, zv.y, zv.z, zv.w};
    float g[8]; float ss = 0.f;
#pragma unroll
    for (int i = 0; i < 8; ++i) {
        unsigned short yu = (i & 1) ? (unsigned short)(yw[i >> 1] >> 16) : (unsigned short)(yw[i >> 1] & 0xffff);
        unsigned short zu = (i & 1) ? (unsigned short)(zw[i >> 1] >> 16) : (unsigned short)(zw[i >> 1] & 0xffff);
        float y = b2f(yu), z = b2f(zu);
        float gv = y * silu_f(z);
        g[i] = gv; ss += gv * gv;
    }
#pragma unroll
    for (int m = 1; m < 64; m <<= 1) ss += __shfl_xor(ss, m, 64);
    __shared__ float red[4];
    if ((tid & 63) == 0) red[tid >> 6] = ss;
    __syncthreads();
    float tot = red[0] + red[1] + red[2] + red[3];
    float sc = rsqrtf(tot * (1.f / 2048.f) + 1e-5f);
    union { unsigned short s[8]; uint4 u; } o;
#pragma unroll
    for (int i = 0; i < 8; ++i) o.s[i] = f2b(g[i] * sc * nw[c0 + i]);
    *(uint4*)(yg + ((size_t)d * RTOT + r) * DI + c0) = o.u;
}

// ---------------- host ----------------
extern "C" void kernel_launch(void* const* d_in, const int* in_sizes, int n_in,
                              void* d_out, int out_size, void* d_ws, size_t ws_size,
                              hipStream_t stream)
{
    const float* x     = (const float*)d_in[0];
    const float* fin   = (const float*)d_in[1];
    const float* fcw   = (const float*)d_in[2];
    const float* fcb   = (const float*)d_in[3];
    const float* fdtb  = (const float*)d_in[4];
    const float* fAlog = (const float*)d_in[5];
    const float* fDp   = (const float*)d_in[6];
    const float* fnw   = (const float*)d_in[7];
    const float* fout  = (const float*)d_in[8];
    const float* bin   = (const float*)d_in[9];
    const float* bcw   = (const float*)d_in[10];
    const float* bcb   = (const float*)d_in[11];
    const float* bdtb  = (const float*)d_in[12];
    const float* bAlog = (const float*)d_in[13];
    const float* bDp   = (const float*)d_in[14];
    const float* bnw   = (const float*)d_in[15];
    const float* bout  = (const float*)d_in[16];
    const float* lw    = (const float*)d_in[17];
    const float* lsc   = (const float*)d_in[18];

    char* w = (char*)d_ws;
    auto alloc = [&](size_t bytes) { char* p = w; w += (bytes + 255) & ~(size_t)255; return p; };
    unsigned short* xb  = (unsigned short*)alloc((size_t)RTOT * DM * 2);
    // win padded to 8448 rows so GEMM A's last 256-col block reads in-bounds
    unsigned short* win = (unsigned short*)alloc((size_t)(NW + 128) * DM * 2);
    unsigned short* wo  = (unsigned short*)alloc((size_t)2 * DM * DI * 2);
    unsigned short* wl  = (unsigned short*)alloc((size_t)DM * DI * 2);
    unsigned short* zx  = (unsigned short*)alloc((size_t)RTOT * NW * 2);
    unsigned short* xs  = (unsigned short*)alloc((size_t)2 * RTOT * DI * 2);
    float* Bc  = (float*)alloc((size_t)2 * RTOT * NSTATE * 4);
    float* Cc  = (float*)alloc((size_t)2 * RTOT * NSTATE * 4);
    float* dtb = (float*)alloc((size_t)2 * RTOT * NH * 4);
    float* dAb = (float*)alloc((size_t)2 * RTOT * NH * 4);
    unsigned short* yb  = (unsigned short*)alloc((size_t)2 * RTOT * DI * 2);
    unsigned short* yg  = (unsigned short*)alloc((size_t)2 * RTOT * DI * 2);
    unsigned short* hbi = (unsigned short*)alloc((size_t)RTOT * DI * 2);
    float* Pbuf = (float*)alloc((size_t)128 * NCH * 4);
    // Sbuf/Hbuf alias xb and win (dead after GEMM A).
    float* Sbuf = (float*)xb;
    float* Hbuf = (float*)win;
    (void)ws_size; (void)in_sizes; (void)n_in; (void)out_size;

    // batched weight/activation converts to bf16 (one dispatch)
    CvtJobs jobs;
    jobs.src[0] = x;    jobs.dst[0] = xb;                        jobs.n4[0] = RTOT * DM / 4;
    jobs.src[1] = fin;  jobs.dst[1] = win;                       jobs.n4[1] = DIP * DM / 4;
    jobs.src[2] = bin;  jobs.dst[2] = win + (size_t)DIP * DM;    jobs.n4[2] = DIP * DM / 4;
    jobs.src[3] = fout; jobs.dst[3] = wo;                        jobs.n4[3] = DM * DI / 4;
    jobs.src[4] = bout; jobs.dst[4] = wo + (size_t)DM * DI;      jobs.n4[4] = DM * DI / 4;
    jobs.src[5] = lw;   jobs.dst[5] = wl;                        jobs.n4[5] = DM * DI / 4;
    cvtb_kernel<<<dim3((DIP * DM / 4 + 255) / 256, 6), 256, 0, stream>>>(jobs);

    // GEMM A: zxbcdt both dirs (stacked weights). M=4096, N=8320 (pad->8448), K=1024
    gemmP_kernel<128, 256, 1><<<dim3(33, RTOT / 128), 512, 0, stream>>>(
        xb, win, nullptr, nullptr, zx, NW, DM, NW, 0, 0, nullptr, nullptr);

    // conv + silu + split (fwd causal, bwd anti-causal), sliding-window
    conv_kernel<<<dim3((CDIM + 255) / 256, LSEQ / TCV, 4), 256, 0, stream>>>(
        zx, fcw, fcb, bcw, bcb, xs, Bc, Cc);

    // dt softplus + dA
    dt_kernel<<<(2 * NB * LSEQ * NH) / 256, 256, 0, stream>>>(
        zx, fdtb, fAlog, bdtb, bAlog, dtb, dAb);

    // chunked scan: A) per-chunk states, B) combine, C) per-chunk scan+y
    chunk_state_kernel<<<dim3(NH, 4, NCH - 1), 64, 0, stream>>>(
        xs, Bc, dtb, dAb, Sbuf, Pbuf);
    chunk_combine_kernel<<<128, 64, 0, stream>>>(Sbuf, Pbuf, Hbuf);
    chunk_scan_kernel<<<dim3(NH, 4, NCH), 64, 0, stream>>>(
        xs, Bc, Cc, dtb, dAb, fDp, bDp, Hbuf, yb);

    // gate + RMSNorm
    gatenorm_kernel<<<dim3(RTOT, 2), 256, 0, stream>>>(yb, zx, fnw, bnw, yg);

    // GEMM B: out_proj both dirs fused (grid.z=2). M=4096, N=1024, K=2048
    gemmP_kernel<128, 256, 1><<<dim3(DM / 256, RTOT / 128, 2), 512, 0, stream>>>(
        yg, wo, yg + (size_t)RTOT * DI, wo + (size_t)DM * DI,
        hbi, DM, DI, DI, 0, DM, nullptr, nullptr);

    // GEMM C: layer out proj + residual epilogue. M=4096, N=1024, K=2048
    gemmP_kernel<128, 128, 2><<<dim3(DM / 128, RTOT / 128), 512, 0, stream>>>(
        hbi, wl, nullptr, nullptr, d_out, DM, DI, DM, 0, 0, x, lsc);
}

// Round 7
// 342.801 us; speedup vs baseline: 1.1210x; 1.0624x over previous
//
#include <hip/hip_runtime.h>

// ---------------- helpers ----------------
typedef __attribute__((ext_vector_type(8))) short bf16x8;   // 8 bf16 (4 VGPRs)
typedef __attribute__((ext_vector_type(4))) float f32x4;
typedef __attribute__((ext_vector_type(2))) long i64x2;     // 16B = 2 fp8 MFMA operands

#define DEV static __device__ __forceinline__

DEV float b2f(unsigned short u) {
    union { unsigned int u; float f; } c; c.u = ((unsigned int)u) << 16; return c.f;
}
DEV unsigned short f2b(float f) {
    union { float f; unsigned int u; } c; c.f = f;
    unsigned int u = c.u + 0x7fffu + ((c.u >> 16) & 1u);
    return (unsigned short)(u >> 16);
}
DEV float silu_f(float v) { return v / (1.f + __expf(-v)); }

// software f32 -> OCP e4m3fn (RNE, saturating). No builtin dependency.
DEV unsigned char f2e4(float x) {
    union { float f; unsigned int u; } c; c.f = x;
    unsigned int s = (c.u >> 24) & 0x80u;
    float a = fabsf(x);
    if (!(a < 448.f)) return (unsigned char)(s | 0x7E);      // saturate
    int ex = (int)((c.u >> 23) & 0xFF) - 127;
    if (ex < -11) return (unsigned char)s;
    unsigned int m = (c.u & 0x7FFFFF) | 0x800000;
    int shift = (ex >= -6) ? 20 : (20 + (-6 - ex));
    unsigned int r = m >> shift;
    unsigned int rem = m & ((1u << shift) - 1u);
    unsigned int half = 1u << (shift - 1);
    if (rem > half || (rem == half && (r & 1u))) r++;
    if (ex >= -6) {
        int e8 = ex + 7;
        if (r >= 16u) { r >>= 1; e8++; }
        if (e8 > 15 || (e8 == 15 && (r & 7u) == 7u)) return (unsigned char)(s | 0x7E);
        return (unsigned char)(s | ((unsigned)e8 << 3) | (r & 7u));
    } else {
        if (r >= 8u) return (unsigned char)(s | 0x08);        // rounds to min normal
        return (unsigned char)(s | r);
    }
}

#define GLD16(gp, lp) __builtin_amdgcn_global_load_lds( \
    (const __attribute__((address_space(1))) void*)(gp), \
    (__attribute__((address_space(3))) void*)(lp), 16, 0, 0)

// sizes
#define LSEQ 2048
#define NB 2
#define RTOT 4096          // NB*LSEQ
#define DM 1024
#define DI 2048
#define NH 32
#define HP 64
#define NSTATE 16
#define CDIM 2080
#define DIP 4160           // per-dir in_proj width
#define NW 8320            // stacked width
#define NWP 8448           // padded to 256
#define QCH 64             // scan chunk length
#define NCH (LSEQ / QCH)   // 32 chunks

// ---------------- batched f32 -> bf16 convert (weights for GEMM B/C) ----------------
struct CvtJobs {
    const float* src[3];
    unsigned short* dst[3];
    int n4[3];
};
__global__ __launch_bounds__(256) void cvtb_kernel(CvtJobs j) {
    const int jb = blockIdx.y;
    const int i = blockIdx.x * 256 + threadIdx.x;
    if (i >= j.n4[jb]) return;
    float4 v = ((const float4*)j.src[jb])[i];
    union { unsigned short s[4]; uint2 u; } p;
    p.s[0] = f2b(v.x); p.s[1] = f2b(v.y); p.s[2] = f2b(v.z); p.s[3] = f2b(v.w);
    ((uint2*)j.dst[jb])[i] = p.u;
}

// ---------------- f32 -> fp8 e4m3, K-permuted in 64-col blocks ----------------
// Within each 64-col block: out_pos = lq*16 + ks*8 + j  for col = ks*32 + lq*8 + j.
// One thread emits 8 bytes (one (blk,lq,ks) group). rows >= rows0+rows1 -> zero pad.
__global__ __launch_bounds__(256) void cvt8_kernel(
    const float* __restrict__ s0, const float* __restrict__ s1,
    unsigned char* __restrict__ dst, int rows0, int rows1, int rowstot)
{
    int gid = blockIdx.x * 256 + threadIdx.x;   // thread = 8 cols, 128 threads/row (K=1024)
    if (gid >= rowstot * 128) return;
    int row = gid >> 7, g = gid & 127;
    int blk = g >> 3, sub = g & 7;
    int lq = sub >> 1, ks = sub & 1;
    unsigned char out[8];
    if (row < rows0 + rows1) {
        const float* src = (row < rows0 ? s0 + (size_t)row * 1024
                                        : s1 + (size_t)(row - rows0) * 1024)
                           + blk * 64 + ks * 32 + lq * 8;
        float4 v0 = *(const float4*)src;
        float4 v1 = *(const float4*)(src + 4);
        out[0] = f2e4(v0.x); out[1] = f2e4(v0.y); out[2] = f2e4(v0.z); out[3] = f2e4(v0.w);
        out[4] = f2e4(v1.x); out[5] = f2e4(v1.y); out[6] = f2e4(v1.z); out[7] = f2e4(v1.w);
    } else {
#pragma unroll
        for (int i = 0; i < 8; ++i) out[i] = 0;
    }
    *(uint2*)(dst + (size_t)row * 1024 + blk * 64 + sub * 8) = *(uint2*)out;
}

// ---------------- FP8 MFMA GEMM (GEMM A): BM=128, BN=256, BK=64, single-barrier pipeline ----------------
// LDS: row-pair lines of 128B, chunk XOR-swizzle key (line&7). 3 buffers, stage t+2, vmcnt(3).
__global__ void __launch_bounds__(512, 4)
gemm8_kernel(
    const unsigned char* __restrict__ A8, const unsigned char* __restrict__ B8,
    unsigned short* __restrict__ Cout, int Ntot, int K, int ldc)
{
    constexpr int ABYTES = 128 * 64;       // 8 KiB
    constexpr int BBYTES = 256 * 64;       // 16 KiB
    constexpr int BUFB = ABYTES + BBYTES;  // 24 KiB
    __shared__ unsigned char lds8[3 * BUFB];

    // bijective XCD chunk + gm=8 group walk
    const int nbx = gridDim.x, nby = gridDim.y;
    const int nwg = nbx * nby;
    int id = blockIdx.y * nbx + blockIdx.x;
    {
        const int q = nwg >> 3, r = nwg & 7;
        const int xcd = id & 7, off = id >> 3;
        id = (xcd < r) ? (xcd * (q + 1) + off) : (r * (q + 1) + (xcd - r) * q + off);
    }
    const int gm = 8;
    const int gidx = id / (gm * nbx);
    const int rem  = id - gidx * gm * nbx;
    const int width = min(gm, nby - gidx * gm);
    const int bm = (gidx * gm + rem % width) * 128;
    const int bn = (rem / width) * 256;

    const int tid  = threadIdx.x;
    const int wave = tid >> 6, lane = tid & 63;
    const int wm = wave >> 2, wn = wave & 3;
    const int lr = lane & 15, lq = lane >> 4;
    const int KT = K >> 6;

    int aoff[4], boff[4];
#pragma unroll
    for (int mf = 0; mf < 4; ++mf) {
        int row = wm * 64 + mf * 16 + lr;
        int L = row >> 1, cc = ((row & 1) << 2) | lq;
        aoff[mf] = L * 128 + ((cc ^ (L & 7)) << 4);
    }
#pragma unroll
    for (int ni = 0; ni < 4; ++ni) {
        int row = wn * 64 + ni * 16 + lr;
        int L = row >> 1, cc = ((row & 1) << 2) | lq;
        boff[ni] = ABYTES + L * 128 + ((cc ^ (L & 7)) << 4);
    }

    auto stage = [&](int ktt, int sbuf) {
        {   // A: 8 KiB, one gload/thread
            int L = tid >> 3, cp = tid & 7;
            int cc = cp ^ (L & 7);
            int srow = bm + 2 * L + (cc >> 2);
            const unsigned char* src = A8 + (size_t)srow * K + (ktt << 6) + ((cc & 3) << 4);
            GLD16(src, &lds8[sbuf * BUFB + ((tid >> 6) << 10)]);
        }
#pragma unroll
        for (int q = 0; q < 2; ++q) {   // B: 16 KiB, two gloads/thread
            int u = q * 512 + tid;
            int L = u >> 3, cp = u & 7;
            int cc = cp ^ (L & 7);
            int srow = bn + 2 * L + (cc >> 2);
            const unsigned char* src = B8 + (size_t)srow * K + (ktt << 6) + ((cc & 3) << 4);
            GLD16(src, &lds8[sbuf * BUFB + ABYTES + q * 8192 + ((tid >> 6) << 10)]);
        }
    };

    f32x4 acc[4][4];
#pragma unroll
    for (int i = 0; i < 4; ++i)
#pragma unroll
        for (int j = 0; j < 4; ++j) acc[i][j] = (f32x4){0.f, 0.f, 0.f, 0.f};

    stage(0, 0);
    if (KT > 1) stage(1, 1);
    asm volatile("s_waitcnt vmcnt(3)" ::: "memory");
    __builtin_amdgcn_sched_barrier(0);
    __builtin_amdgcn_s_barrier();
    __builtin_amdgcn_sched_barrier(0);

    int cur = 0, stg = 2;
    for (int kt = 0; kt < KT; ++kt) {
        const int cb = cur * BUFB;
        const bool dostage = (kt + 2) < KT;
        if (dostage) stage(kt + 2, stg);

        i64x2 av[4], bv[4];
#pragma unroll
        for (int mf = 0; mf < 4; ++mf) av[mf] = *(const i64x2*)&lds8[cb + aoff[mf]];
#pragma unroll
        for (int ni = 0; ni < 4; ++ni) bv[ni] = *(const i64x2*)&lds8[cb + boff[ni]];

        __builtin_amdgcn_s_setprio(1);
#pragma unroll
        for (int mf = 0; mf < 4; ++mf)
#pragma unroll
            for (int ni = 0; ni < 4; ++ni) {
                acc[mf][ni] = __builtin_amdgcn_mfma_f32_16x16x32_fp8_fp8(av[mf].x, bv[ni].x, acc[mf][ni], 0, 0, 0);
                acc[mf][ni] = __builtin_amdgcn_mfma_f32_16x16x32_fp8_fp8(av[mf].y, bv[ni].y, acc[mf][ni], 0, 0, 0);
            }
        __builtin_amdgcn_s_setprio(0);

        if (dostage) { asm volatile("s_waitcnt vmcnt(3)" ::: "memory"); }
        else         { asm volatile("s_waitcnt vmcnt(0)" ::: "memory"); }
        __builtin_amdgcn_sched_barrier(0);
        __builtin_amdgcn_s_barrier();
        __builtin_amdgcn_sched_barrier(0);

        cur = (cur == 2) ? 0 : cur + 1;
        stg = (stg == 2) ? 0 : stg + 1;
    }

#pragma unroll
    for (int mf = 0; mf < 4; ++mf)
#pragma unroll
        for (int ni = 0; ni < 4; ++ni)
#pragma unroll
            for (int r = 0; r < 4; ++r) {
                int grow = bm + wm * 64 + mf * 16 + lq * 4 + r;
                int gcol = bn + wn * 64 + ni * 16 + lr;
                if (gcol < Ntot)
                    Cout[(size_t)grow * ldc + gcol] = f2b(acc[mf][ni][r]);
            }
}

// ---------------- bf16 pipelined GEMM (B/C), unchanged R6 engine ----------------
template<int BM, int BN, int EPI>
__global__ void __launch_bounds__(512, 4)
gemmP_kernel(
    const unsigned short* __restrict__ A0, const unsigned short* __restrict__ BT0,
    const unsigned short* __restrict__ A1, const unsigned short* __restrict__ BT1,
    void* __restrict__ Cout,
    int Ntot, int K, int ldc, int coff0, int coff1,
    const float* __restrict__ ex, const float* __restrict__ esc)
{
    constexpr int MF = BM / 32;
    constexpr int NI = BN / 64;
    constexpr int GA = BM / 128, GB = BN / 128;
    constexpr int GT = GA + GB;
    constexpr int ASH = BM * 32;
    constexpr int BSH = BN * 32;
    constexpr int BUFS = ASH + BSH;
    __shared__ unsigned short lds[3 * BUFS];

    const unsigned short* __restrict__ A  = blockIdx.z ? A1 : A0;
    const unsigned short* __restrict__ BT = blockIdx.z ? BT1 : BT0;
    const int coff = blockIdx.z ? coff1 : coff0;

    const int nbx = gridDim.x, nby = gridDim.y;
    const int nwg = nbx * nby;
    int id = blockIdx.y * nbx + blockIdx.x;
    {
        const int q = nwg >> 3, r = nwg & 7;
        const int xcd = id & 7, off = id >> 3;
        id = (xcd < r) ? (xcd * (q + 1) + off) : (r * (q + 1) + (xcd - r) * q + off);
    }
    const int gm = 8;
    const int gidx = id / (gm * nbx);
    const int rem  = id - gidx * gm * nbx;
    const int width = min(gm, nby - gidx * gm);
    const int bm = (gidx * gm + rem % width) * BM;
    const int bn = (rem / width) * BN;

    const int tid  = threadIdx.x;
    const int wave = tid >> 6, lane = tid & 63;
    const int wm = wave >> 2, wn = wave & 3;
    const int lr = lane & 15, lq = lane >> 4;
    const int KT = K >> 5;

    int aoff[MF], boff[NI];
#pragma unroll
    for (int mf = 0; mf < MF; ++mf) {
        int row = wm * (BM / 2) + mf * 16 + lr;
        aoff[mf] = row * 32 + ((lq ^ ((row ^ (row >> 2)) & 3)) << 3);
    }
#pragma unroll
    for (int ni = 0; ni < NI; ++ni) {
        int row = wn * (BN / 4) + ni * 16 + lr;
        boff[ni] = ASH + row * 32 + ((lq ^ ((row ^ (row >> 2)) & 3)) << 3);
    }

    auto stageA = [&](int ktt, int sbuf) {
#pragma unroll
        for (int q = 0; q < GA; ++q) {
            int _r = q * 128 + (tid >> 2);
            const unsigned short* src = A + (size_t)(bm + _r) * K + (ktt << 5)
                                          + (((tid & 3) ^ ((_r ^ (_r >> 2)) & 3)) << 3);
            GLD16(src, &lds[sbuf * BUFS + q * 4096 + ((tid >> 6) << 9)]);
        }
    };
    auto stageB = [&](int ktt, int sbuf) {
#pragma unroll
        for (int q = 0; q < GB; ++q) {
            int _r = q * 128 + (tid >> 2);
            const unsigned short* src = BT + (size_t)(bn + _r) * K + (ktt << 5)
                                          + (((tid & 3) ^ ((_r ^ (_r >> 2)) & 3)) << 3);
            GLD16(src, &lds[sbuf * BUFS + ASH + q * 4096 + ((tid >> 6) << 9)]);
        }
    };

    f32x4 acc[MF][NI];
#pragma unroll
    for (int i = 0; i < MF; ++i)
#pragma unroll
        for (int j = 0; j < NI; ++j) acc[i][j] = (f32x4){0.f, 0.f, 0.f, 0.f};

    stageA(0, 0); stageB(0, 0);
    if (KT > 1) { stageA(1, 1); stageB(1, 1); }
    if constexpr (GT == 3) { asm volatile("s_waitcnt vmcnt(3)" ::: "memory"); }
    else                   { asm volatile("s_waitcnt vmcnt(2)" ::: "memory"); }
    __builtin_amdgcn_sched_barrier(0);
    __builtin_amdgcn_s_barrier();
    __builtin_amdgcn_sched_barrier(0);

    int cur = 0, stg = 2;
    for (int kt = 0; kt < KT; ++kt) {
        const int cb = cur * BUFS;
        const bool dostage = (kt + 2) < KT;
        if (dostage) { stageA(kt + 2, stg); stageB(kt + 2, stg); }

        bf16x8 af[MF], bf[NI];
#pragma unroll
        for (int mf = 0; mf < MF; ++mf) af[mf] = *(const bf16x8*)&lds[cb + aoff[mf]];
#pragma unroll
        for (int ni = 0; ni < NI; ++ni) bf[ni] = *(const bf16x8*)&lds[cb + boff[ni]];

        __builtin_amdgcn_s_setprio(1);
#pragma unroll
        for (int mf = 0; mf < MF; ++mf)
#pragma unroll
            for (int ni = 0; ni < NI; ++ni)
                acc[mf][ni] = __builtin_amdgcn_mfma_f32_16x16x32_bf16(af[mf], bf[ni], acc[mf][ni], 0, 0, 0);
        __builtin_amdgcn_s_setprio(0);

        if (dostage) {
            if constexpr (GT == 3) { asm volatile("s_waitcnt vmcnt(3)" ::: "memory"); }
            else                   { asm volatile("s_waitcnt vmcnt(2)" ::: "memory"); }
        } else {
            asm volatile("s_waitcnt vmcnt(0)" ::: "memory");
        }
        __builtin_amdgcn_sched_barrier(0);
        __builtin_amdgcn_s_barrier();
        __builtin_amdgcn_sched_barrier(0);

        cur = (cur == 2) ? 0 : cur + 1;
        stg = (stg == 2) ? 0 : stg + 1;
    }

#pragma unroll
    for (int mf = 0; mf < MF; ++mf)
#pragma unroll
        for (int ni = 0; ni < NI; ++ni)
#pragma unroll
            for (int r = 0; r < 4; ++r) {
                int grow = bm + wm * (BM / 2) + mf * 16 + lq * 4 + r;
                int gcol = bn + wn * (BN / 4) + ni * 16 + lr;
                float v = acc[mf][ni][r];
                if (EPI == 1) {
                    if (gcol < Ntot)
                        ((unsigned short*)Cout)[(size_t)grow * ldc + coff + gcol] = f2b(v);
                } else {
                    size_t idx = (size_t)grow * ldc + gcol;
                    ((float*)Cout)[idx] = ex[idx] + v * esc[gcol];
                }
            }
}

// ---------------- depthwise conv + silu + split, with dt/dA fused in last block ----------------
#define TCV 64
__global__ __launch_bounds__(256) void conv_kernel(
    const unsigned short* __restrict__ ZX,   // [4096][8320] bf16
    const float* __restrict__ cwF, const float* __restrict__ cbF,
    const float* __restrict__ cwB, const float* __restrict__ cbB,
    const float* __restrict__ dtbiasF, const float* __restrict__ AlogF,
    const float* __restrict__ dtbiasB, const float* __restrict__ AlogB,
    unsigned short* __restrict__ xs,         // [2][4096][2048] bf16
    float* __restrict__ Bc, float* __restrict__ Cc,
    float* __restrict__ dtb, float* __restrict__ dAb)
{
    const int c = blockIdx.x * 256 + threadIdx.x;
    const int t0 = blockIdx.y * TCV;
    const int db = blockIdx.z;
    const int d = db >> 1, b = db & 1;

    if (c >= CDIM) {                        // dt path (32 channels)
        if (c >= CDIM + NH) return;
        const int h = c - CDIM;
        const float bias = (d ? dtbiasB : dtbiasF)[h];
        const float A = -__expf((d ? AlogB : AlogF)[h]);
        const unsigned short* zp = ZX + (size_t)d * DIP + (DI + CDIM) + h;
#pragma unroll 4
        for (int i = 0; i < TCV; ++i) {
            int t = t0 + i;
            float raw = b2f(zp[((size_t)b * LSEQ + t) * NW]);
            float xv = raw + bias;
            float dtv = (xv > 20.f) ? xv : __logf(1.f + __expf(xv));
            int idx = (db * LSEQ + t) * NH + h;
            dtb[idx] = dtv;
            dAb[idx] = __expf(dtv * A);
        }
        return;
    }

    const float* cw = d ? cwB : cwF;
    const float* cb = d ? cbB : cbF;
    float4 w = *(const float4*)&cw[c * 4];
    const float bias = cb[c];
    const unsigned short* base = ZX + (size_t)d * DIP + DI + c;

    auto ldg = [&](int t) -> float {
        return (t >= 0 && t < LSEQ) ? b2f(base[(size_t)(b * LSEQ + t) * NW]) : 0.f;
    };
    auto emit = [&](int t, float acc) {
        float v = silu_f(acc);
        const int row = b * LSEQ + t;
        if (c < DI) {
            xs[((size_t)d * RTOT + row) * DI + c] = f2b(v);
        } else if (c < DI + NSTATE) {
            Bc[((size_t)db * LSEQ + t) * NSTATE + (c - DI)] = v;
        } else {
            Cc[((size_t)db * LSEQ + t) * NSTATE + (c - DI - NSTATE)] = v;
        }
    };

    if (d == 0) {
        float v0 = ldg(t0 - 3), v1 = ldg(t0 - 2), v2 = ldg(t0 - 1), vt = ldg(t0);
#pragma unroll 4
        for (int i = 0; i < TCV; ++i) {
            float vn = (i < TCV - 1) ? ldg(t0 + i + 1) : 0.f;
            emit(t0 + i, bias + w.x * v0 + w.y * v1 + w.z * v2 + w.w * vt);
            v0 = v1; v1 = v2; v2 = vt; vt = vn;
        }
    } else {
        float v3 = ldg(t0 + TCV + 2), v2 = ldg(t0 + TCV + 1), v1 = ldg(t0 + TCV), vt = ldg(t0 + TCV - 1);
#pragma unroll 4
        for (int i = TCV - 1; i >= 0; --i) {
            float vn = (i > 0) ? ldg(t0 + i - 1) : 0.f;
            emit(t0 + i, bias + w.w * vt + w.z * v1 + w.y * v2 + w.x * v3);
            v3 = v2; v2 = v1; v1 = vt; vt = vn;
        }
    }
}

#define LD16V(dst, ptr) do { const float4* _p = (const float4*)(ptr); \
    float4 _q0 = _p[0], _q1 = _p[1], _q2 = _p[2], _q3 = _p[3]; \
    dst[0]=_q0.x; dst[1]=_q0.y; dst[2]=_q0.z; dst[3]=_q0.w; \
    dst[4]=_q1.x; dst[5]=_q1.y; dst[6]=_q1.z; dst[7]=_q1.w; \
    dst[8]=_q2.x; dst[9]=_q2.y; dst[10]=_q2.z; dst[11]=_q2.w; \
    dst[12]=_q3.x; dst[13]=_q3.y; dst[14]=_q3.z; dst[15]=_q3.w; } while (0)

#define ST16V(ptr, src) do { float4* _p = (float4*)(ptr); \
    _p[0] = make_float4(src[0],src[1],src[2],src[3]); \
    _p[1] = make_float4(src[4],src[5],src[6],src[7]); \
    _p[2] = make_float4(src[8],src[9],src[10],src[11]); \
    _p[3] = make_float4(src[12],src[13],src[14],src[15]); } while (0)

// ---------------- pass A: per-chunk zero-init state + decay product ----------------
__global__ __launch_bounds__(64) void chunk_state_kernel(
    const unsigned short* __restrict__ xs,
    const float* __restrict__ Bc,
    const float* __restrict__ dtb, const float* __restrict__ dAb,
    float* __restrict__ Sbuf,               // [128][NCH][64][16]
    float* __restrict__ Pbuf)               // [128][NCH]
{
    const int h = blockIdx.x, db = blockIdx.y, c = blockIdx.z;
    const int d = db >> 1, b = db & 1;
    const int lane = threadIdx.x;
    float hs[16];
#pragma unroll
    for (int n = 0; n < 16; ++n) hs[n] = 0.f;
    float pacc = 1.f;
    const size_t dbase = (size_t)d * RTOT;
    const int s0 = c * QCH;

    float Bs[16], xv, dtv, dAv;
    float Bn[16], xn, dtn, dAn;
    {
        const int t = d ? (LSEQ - 1 - s0) : s0;
        const size_t row = (size_t)b * LSEQ + t, rdb = (size_t)db * LSEQ + t;
        xv  = b2f(xs[(dbase + row) * DI + h * HP + lane]);
        dtv = dtb[rdb * 32 + h]; dAv = dAb[rdb * 32 + h];
        LD16V(Bs, Bc + rdb * 16);
    }
#pragma unroll 2
    for (int i = 0; i < QCH; ++i) {
        const int sn = s0 + ((i < QCH - 1) ? i + 1 : i);
        const int tn = d ? (LSEQ - 1 - sn) : sn;
        {
            const size_t rown = (size_t)b * LSEQ + tn, rdbn = (size_t)db * LSEQ + tn;
            xn  = b2f(xs[(dbase + rown) * DI + h * HP + lane]);
            dtn = dtb[rdbn * 32 + h]; dAn = dAb[rdbn * 32 + h];
            LD16V(Bn, Bc + rdbn * 16);
        }
        const float dtx = dtv * xv;
#pragma unroll
        for (int n = 0; n < 16; ++n) hs[n] = fmaf(hs[n], dAv, Bs[n] * dtx);
        pacc *= dAv;
        xv = xn; dtv = dtn; dAv = dAn;
#pragma unroll
        for (int n = 0; n < 16; ++n) Bs[n] = Bn[n];
    }
    float* Sp = Sbuf + (((size_t)(db * NH + h)) * NCH + c) * 1024 + lane * 16;
    ST16V(Sp, hs);
    if (lane == 0) Pbuf[(db * NH + h) * NCH + c] = pacc;
}

// ---------------- pass B: sequential combine over chunks (tiny) ----------------
__global__ __launch_bounds__(64) void chunk_combine_kernel(
    const float* __restrict__ Sbuf, const float* __restrict__ Pbuf,
    float* __restrict__ Hbuf)               // [128][NCH][64][16]
{
    const int idx = blockIdx.x;
    const int lane = threadIdx.x;
    float hs[16];
#pragma unroll
    for (int n = 0; n < 16; ++n) hs[n] = 0.f;
    float* H0 = Hbuf + ((size_t)idx * NCH) * 1024 + lane * 16;
    ST16V(H0, hs);
    for (int c = 0; c < NCH - 1; ++c) {
        const float* Sp = Sbuf + ((size_t)idx * NCH + c) * 1024 + lane * 16;
        float S[16];
        LD16V(S, Sp);
        const float P = Pbuf[idx * NCH + c];
#pragma unroll
        for (int n = 0; n < 16; ++n) hs[n] = fmaf(hs[n], P, S[n]);
        float* Hp = Hbuf + ((size_t)idx * NCH + c + 1) * 1024 + lane * 16;
        ST16V(Hp, hs);
    }
}

// ---------------- pass C: per-chunk scan from Hinit, emit y ----------------
__global__ __launch_bounds__(64) void chunk_scan_kernel(
    const unsigned short* __restrict__ xs,
    const float* __restrict__ Bc, const float* __restrict__ Cc,
    const float* __restrict__ dtb, const float* __restrict__ dAb,
    const float* __restrict__ DpF, const float* __restrict__ DpB,
    const float* __restrict__ Hbuf,
    unsigned short* __restrict__ ybuf)       // [2][4096][2048]
{
    const int h = blockIdx.x, db = blockIdx.y, c = blockIdx.z;
    const int d = db >> 1, b = db & 1;
    const int lane = threadIdx.x;
    const float Dp = (d ? DpB : DpF)[h];
    float hs[16];
    {
        const float* Hp = Hbuf + ((size_t)(db * NH + h) * NCH + c) * 1024 + lane * 16;
        LD16V(hs, Hp);
    }
    const size_t dbase = (size_t)d * RTOT;
    const int s0 = c * QCH;

    float Bs[16], Cs[16], xv, dtv, dAv;
    float Bn[16], Cn[16], xn, dtn, dAn;
    {
        const int t = d ? (LSEQ - 1 - s0) : s0;
        const size_t row = (size_t)b * LSEQ + t, rdb = (size_t)db * LSEQ + t;
        xv  = b2f(xs[(dbase + row) * DI + h * HP + lane]);
        dtv = dtb[rdb * 32 + h]; dAv = dAb[rdb * 32 + h];
        LD16V(Bs, Bc + rdb * 16);
        LD16V(Cs, Cc + rdb * 16);
    }
#pragma unroll 2
    for (int i = 0; i < QCH; ++i) {
        const int sn = s0 + ((i < QCH - 1) ? i + 1 : i);
        const int tn = d ? (LSEQ - 1 - sn) : sn;
        {
            const size_t rown = (size_t)b * LSEQ + tn, rdbn = (size_t)db * LSEQ + tn;
            xn  = b2f(xs[(dbase + rown) * DI + h * HP + lane]);
            dtn = dtb[rdbn * 32 + h]; dAn = dAb[rdbn * 32 + h];
            LD16V(Bn, Bc + rdbn * 16);
            LD16V(Cn, Cc + rdbn * 16);
        }
        const float dtx = dtv * xv;
        float yq[4] = {0.f, 0.f, 0.f, 0.f};
#pragma unroll
        for (int n = 0; n < 16; ++n) {
            hs[n] = fmaf(hs[n], dAv, Bs[n] * dtx);
            yq[n & 3] = fmaf(Cs[n], hs[n], yq[n & 3]);
        }
        const int t = d ? (LSEQ - 1 - (s0 + i)) : (s0 + i);
        const size_t row = (size_t)b * LSEQ + t;
        ybuf[(dbase + row) * DI + h * HP + lane] = f2b(((yq[0] + yq[1]) + (yq[2] + yq[3])) + Dp * xv);

        xv = xn; dtv = dtn; dAv = dAn;
#pragma unroll
        for (int n = 0; n < 16; ++n) { Bs[n] = Bn[n]; Cs[n] = Cn[n]; }
    }
}

// ---------------- gate (silu(z)) + RMSNorm -> bf16 ----------------
__global__ __launch_bounds__(256) void gatenorm_kernel(
    const unsigned short* __restrict__ ybuf, const unsigned short* __restrict__ ZX,
    const float* __restrict__ nwF, const float* __restrict__ nwB,
    unsigned short* __restrict__ yg)
{
    const int r = blockIdx.x;
    const int d = blockIdx.y;
    const int tid = threadIdx.x;
    const float* nw = d ? nwB : nwF;
    const int c0 = tid * 8;
    const unsigned short* yp = ybuf + ((size_t)d * RTOT + r) * DI + c0;
    const unsigned short* zp = ZX + (size_t)r * NW + d * DIP + c0;
    uint4 yv = *(const uint4*)yp;
    uint4 zv = *(const uint4*)zp;
    unsigned int yw[4] = {yv.x, yv.y, yv.z, yv.w};
    unsigned int zw[4] = {zv.x, zv.y, zv.z, zv.w};
    float g[8]; float ss = 0.f;
#pragma unroll
    for (int i = 0; i < 8; ++i) {
        unsigned short yu = (i & 1) ? (unsigned short)(yw[i >> 1] >> 16) : (unsigned short)(yw[i >> 1] & 0xffff);
        unsigned short zu = (i & 1) ? (unsigned short)(zw[i >> 1] >> 16) : (unsigned short)(zw[i >> 1] & 0xffff);
        float y = b2f(yu), z = b2f(zu);
        float gv = y * silu_f(z);
        g[i] = gv; ss += gv * gv;
    }
#pragma unroll
    for (int m = 1; m < 64; m <<= 1) ss += __shfl_xor(ss, m, 64);
    __shared__ float red[4];
    if ((tid & 63) == 0) red[tid >> 6] = ss;
    __syncthreads();
    float tot = red[0] + red[1] + red[2] + red[3];
    float sc = rsqrtf(tot * (1.f / 2048.f) + 1e-5f);
    union { unsigned short s[8]; uint4 u; } o;
#pragma unroll
    for (int i = 0; i < 8; ++i) o.s[i] = f2b(g[i] * sc * nw[c0 + i]);
    *(uint4*)(yg + ((size_t)d * RTOT + r) * DI + c0) = o.u;
}

// ---------------- host ----------------
extern "C" void kernel_launch(void* const* d_in, const int* in_sizes, int n_in,
                              void* d_out, int out_size, void* d_ws, size_t ws_size,
                              hipStream_t stream)
{
    const float* x     = (const float*)d_in[0];
    const float* fin   = (const float*)d_in[1];
    const float* fcw   = (const float*)d_in[2];
    const float* fcb   = (const float*)d_in[3];
    const float* fdtb  = (const float*)d_in[4];
    const float* fAlog = (const float*)d_in[5];
    const float* fDp   = (const float*)d_in[6];
    const float* fnw   = (const float*)d_in[7];
    const float* fout  = (const float*)d_in[8];
    const float* bin   = (const float*)d_in[9];
    const float* bcw   = (const float*)d_in[10];
    const float* bcb   = (const float*)d_in[11];
    const float* bdtb  = (const float*)d_in[12];
    const float* bAlog = (const float*)d_in[13];
    const float* bDp   = (const float*)d_in[14];
    const float* bnw   = (const float*)d_in[15];
    const float* bout  = (const float*)d_in[16];
    const float* lw    = (const float*)d_in[17];
    const float* lsc   = (const float*)d_in[18];

    char* w = (char*)d_ws;
    auto alloc = [&](size_t bytes) { char* p = w; w += (bytes + 255) & ~(size_t)255; return p; };
    unsigned char*  xb8  = (unsigned char*)alloc((size_t)RTOT * DM);       // 4.2 MB fp8-permuted
    unsigned char*  win8 = (unsigned char*)alloc((size_t)NWP * DM);       // 8.65 MB fp8-permuted
    unsigned short* wo  = (unsigned short*)alloc((size_t)2 * DM * DI * 2);
    unsigned short* wl  = (unsigned short*)alloc((size_t)DM * DI * 2);
    unsigned short* zx  = (unsigned short*)alloc((size_t)RTOT * NW * 2);
    unsigned short* xs  = (unsigned short*)alloc((size_t)2 * RTOT * DI * 2);
    float* Bc  = (float*)alloc((size_t)2 * RTOT * NSTATE * 4);
    float* Cc  = (float*)alloc((size_t)2 * RTOT * NSTATE * 4);
    float* dtb = (float*)alloc((size_t)2 * RTOT * NH * 4);
    float* dAb = (float*)alloc((size_t)2 * RTOT * NH * 4);
    unsigned short* yb  = (unsigned short*)alloc((size_t)2 * RTOT * DI * 2);
    unsigned short* yg  = (unsigned short*)alloc((size_t)2 * RTOT * DI * 2);
    unsigned short* hbi = (unsigned short*)alloc((size_t)RTOT * DI * 2);
    float* Pbuf = (float*)alloc((size_t)128 * NCH * 4);
    // Sbuf aliases hbi (live only from GEMM B); Hbuf aliases yg (live only from gatenorm).
    float* Sbuf = (float*)hbi;   // 128*32*64*16*4 = 16.78 MB == hbi bytes
    float* Hbuf = (float*)yg;    // 16.78 MB <= yg 33.5 MB
    (void)ws_size; (void)in_sizes; (void)n_in; (void)out_size;

    // fp8-permuted GEMM-A operands
    cvt8_kernel<<<(RTOT * 128 + 255) / 256, 256, 0, stream>>>(x, x, xb8, RTOT, 0, RTOT);
    cvt8_kernel<<<(NWP * 128 + 255) / 256, 256, 0, stream>>>(fin, bin, win8, DIP, DIP, NWP);

    // GEMM A (fp8): zxbcdt both dirs. M=4096, N=8320(pad 8448), K=1024
    gemm8_kernel<<<dim3(NWP / 256, RTOT / 128), 512, 0, stream>>>(
        xb8, win8, zx, NW, DM, NW);

    // bf16 weights for GEMM B/C
    CvtJobs jobs;
    jobs.src[0] = fout; jobs.dst[0] = wo;                    jobs.n4[0] = DM * DI / 4;
    jobs.src[1] = bout; jobs.dst[1] = wo + (size_t)DM * DI;  jobs.n4[1] = DM * DI / 4;
    jobs.src[2] = lw;   jobs.dst[2] = wl;                    jobs.n4[2] = DM * DI / 4;
    cvtb_kernel<<<dim3((DM * DI / 4 + 255) / 256, 3), 256, 0, stream>>>(jobs);

    // conv + silu + split + fused dt/dA
    conv_kernel<<<dim3((CDIM + NH + 255) / 256, LSEQ / TCV, 4), 256, 0, stream>>>(
        zx, fcw, fcb, bcw, bcb, fdtb, fAlog, bdtb, bAlog, xs, Bc, Cc, dtb, dAb);

    // chunked scan: A) per-chunk states, B) combine, C) per-chunk scan+y
    chunk_state_kernel<<<dim3(NH, 4, NCH - 1), 64, 0, stream>>>(
        xs, Bc, dtb, dAb, Sbuf, Pbuf);
    chunk_combine_kernel<<<128, 64, 0, stream>>>(Sbuf, Pbuf, Hbuf);
    chunk_scan_kernel<<<dim3(NH, 4, NCH), 64, 0, stream>>>(
        xs, Bc, Cc, dtb, dAb, fDp, bDp, Hbuf, yb);

    // gate + RMSNorm
    gatenorm_kernel<<<dim3(RTOT, 2), 256, 0, stream>>>(yb, zx, fnw, bnw, yg);

    // GEMM B: out_proj both dirs fused (grid.z=2). M=4096, N=1024, K=2048
    gemmP_kernel<128, 256, 1><<<dim3(DM / 256, RTOT / 128, 2), 512, 0, stream>>>(
        yg, wo, yg + (size_t)RTOT * DI, wo + (size_t)DM * DI,
        hbi, DM, DI, DI, 0, DM, nullptr, nullptr);

    // GEMM C: layer out proj + residual epilogue. M=4096, N=1024, K=2048
    gemmP_kernel<128, 128, 2><<<dim3(DM / 128, RTOT / 128), 512, 0, stream>>>(
        hbi, wl, nullptr, nullptr, d_out, DM, DI, DM, 0, 0, x, lsc);
}

// Round 8
// 342.391 us; speedup vs baseline: 1.1224x; 1.0012x over previous
//
#include <hip/hip_runtime.h>

// ---------------- helpers ----------------
typedef __attribute__((ext_vector_type(8))) short bf16x8;   // 8 bf16 (4 VGPRs)
typedef __attribute__((ext_vector_type(4))) float f32x4;
typedef __attribute__((ext_vector_type(2))) long i64x2;     // 16B = 2 fp8 MFMA operands

#define DEV static __device__ __forceinline__

DEV float b2f(unsigned short u) {
    union { unsigned int u; float f; } c; c.u = ((unsigned int)u) << 16; return c.f;
}
DEV unsigned short f2b(float f) {
    union { float f; unsigned int u; } c; c.f = f;
    unsigned int u = c.u + 0x7fffu + ((c.u >> 16) & 1u);
    return (unsigned short)(u >> 16);
}
DEV float silu_f(float v) { return v / (1.f + __expf(-v)); }

// software f32 -> OCP e4m3fn (RNE, saturating)
DEV unsigned char f2e4(float x) {
    union { float f; unsigned int u; } c; c.f = x;
    unsigned int s = (c.u >> 24) & 0x80u;
    float a = fabsf(x);
    if (!(a < 448.f)) return (unsigned char)(s | 0x7E);      // saturate (incl NaN->max)
    int ex = (int)((c.u >> 23) & 0xFF) - 127;
    if (ex < -11) return (unsigned char)s;
    unsigned int m = (c.u & 0x7FFFFF) | 0x800000;
    int shift = (ex >= -6) ? 20 : (20 + (-6 - ex));
    unsigned int r = m >> shift;
    unsigned int rem = m & ((1u << shift) - 1u);
    unsigned int half = 1u << (shift - 1);
    if (rem > half || (rem == half && (r & 1u))) r++;
    if (ex >= -6) {
        int e8 = ex + 7;
        if (r >= 16u) { r >>= 1; e8++; }
        if (e8 > 15 || (e8 == 15 && (r & 7u) == 7u)) return (unsigned char)(s | 0x7E);
        return (unsigned char)(s | ((unsigned)e8 << 3) | (r & 7u));
    } else {
        if (r >= 8u) return (unsigned char)(s | 0x08);
        return (unsigned char)(s | r);
    }
}

// K-permutation (64-col blocks): pos(gc) — layout consumed by gemm8's LDS swizzle
DEV int kperm(int gc) {
    return (gc & ~63) | (((gc >> 3) & 3) << 4) | (((gc >> 5) & 1) << 3) | (gc & 7);
}

#define GLD16(gp, lp) __builtin_amdgcn_global_load_lds( \
    (const __attribute__((address_space(1))) void*)(gp), \
    (__attribute__((address_space(3))) void*)(lp), 16, 0, 0)

// sizes
#define LSEQ 2048
#define NB 2
#define RTOT 4096          // NB*LSEQ
#define DM 1024
#define DI 2048
#define NH 32
#define HP 64
#define NSTATE 16
#define CDIM 2080
#define DIP 4160           // per-dir in_proj width
#define NW 8320            // stacked width
#define NWP 8448           // padded to 256
#define QCH 64             // scan chunk length
#define NCH (LSEQ / QCH)   // 32 chunks

// ---------------- batched f32 -> fp8 e4m3 K-permuted convert ----------------
struct Cvt8Jobs {
    const float* s0[4];
    const float* s1[4];
    unsigned char* dst[4];
    int rows0[4], rows1[4], rowstot[4], shift[4];  // shift = log2(K/8)
};
__global__ __launch_bounds__(256) void cvt8b_kernel(Cvt8Jobs j) {
    const int jb = blockIdx.y;
    const int gid = blockIdx.x * 256 + threadIdx.x;
    const int shift = j.shift[jb];
    const int tpr = 1 << shift;
    if (gid >= (j.rowstot[jb] << shift)) return;
    const int row = gid >> shift, g = gid & (tpr - 1);
    const int blk = g >> 3, sub = g & 7, lq = sub >> 1, ks = sub & 1;
    const int K = tpr << 3;
    unsigned char out[8];
    const int r0 = j.rows0[jb], r1 = j.rows1[jb];
    if (row < r0 + r1) {
        const float* src = (row < r0 ? j.s0[jb] + (size_t)row * K
                                     : j.s1[jb] + (size_t)(row - r0) * K)
                           + blk * 64 + ks * 32 + lq * 8;
        float4 v0 = *(const float4*)src;
        float4 v1 = *(const float4*)(src + 4);
        out[0] = f2e4(v0.x); out[1] = f2e4(v0.y); out[2] = f2e4(v0.z); out[3] = f2e4(v0.w);
        out[4] = f2e4(v1.x); out[5] = f2e4(v1.y); out[6] = f2e4(v1.z); out[7] = f2e4(v1.w);
    } else {
#pragma unroll
        for (int i = 0; i < 8; ++i) out[i] = 0;
    }
    *(uint2*)(j.dst[jb] + (size_t)row * K + blk * 64 + sub * 8) = *(uint2*)out;
}

// ---------------- FP8 MFMA GEMM, template <BM,BN,EPI>, single-barrier pipeline ----------------
// BK=64 bytes, 8 waves (2M x 4N), 3 LDS buffers, stage t+2, counted vmcnt(GT).
// LDS: 128B row-pair lines, chunk XOR key (line&7). Operands K-permuted (kperm).
// EPI 1: bf16 store (col clamp at Ntot). EPI 2: f32 ex + v*esc. EPI 3: fp8 kperm store.
template<int BM, int BN, int EPI>
__global__ void __launch_bounds__(512, 4)
gemm8_kernel(
    const unsigned char* __restrict__ A0, const unsigned char* __restrict__ B0,
    const unsigned char* __restrict__ A1, const unsigned char* __restrict__ B1,
    void* __restrict__ Cout,
    int Ntot, int K, int ldc, int coff0, int coff1,
    const float* __restrict__ ex, const float* __restrict__ esc)
{
    constexpr int MF = BM / 32;            // per-wave m-frags
    constexpr int NI = BN / 64;            // per-wave n-frags
    constexpr int GA = BM / 128, GB = BN / 128;
    constexpr int GT = GA + GB;
    constexpr int ABYTES = BM * 64;
    constexpr int BBYTES = BN * 64;
    constexpr int BUFB = ABYTES + BBYTES;
    __shared__ unsigned char lds8[3 * BUFB];

    const unsigned char* __restrict__ A8 = blockIdx.z ? A1 : A0;
    const unsigned char* __restrict__ B8 = blockIdx.z ? B1 : B0;
    const int coff = blockIdx.z ? coff1 : coff0;

    // bijective XCD chunk + gm=8 group walk
    const int nbx = gridDim.x, nby = gridDim.y;
    const int nwg = nbx * nby;
    int id = blockIdx.y * nbx + blockIdx.x;
    {
        const int q = nwg >> 3, r = nwg & 7;
        const int xcd = id & 7, off = id >> 3;
        id = (xcd < r) ? (xcd * (q + 1) + off) : (r * (q + 1) + (xcd - r) * q + off);
    }
    const int gm = 8;
    const int gidx = id / (gm * nbx);
    const int rem  = id - gidx * gm * nbx;
    const int width = min(gm, nby - gidx * gm);
    const int bm = (gidx * gm + rem % width) * BM;
    const int bn = (rem / width) * BN;

    const int tid  = threadIdx.x;
    const int wave = tid >> 6, lane = tid & 63;
    const int wm = wave >> 2, wn = wave & 3;
    const int lr = lane & 15, lq = lane >> 4;
    const int KT = K >> 6;

    int aoff[MF], boff[NI];
#pragma unroll
    for (int mf = 0; mf < MF; ++mf) {
        int row = wm * (BM / 2) + mf * 16 + lr;
        int L = row >> 1, cc = ((row & 1) << 2) | lq;
        aoff[mf] = L * 128 + ((cc ^ (L & 7)) << 4);
    }
#pragma unroll
    for (int ni = 0; ni < NI; ++ni) {
        int row = wn * (BN / 4) + ni * 16 + lr;
        int L = row >> 1, cc = ((row & 1) << 2) | lq;
        boff[ni] = ABYTES + L * 128 + ((cc ^ (L & 7)) << 4);
    }

    auto stage = [&](int ktt, int sbuf) {
#pragma unroll
        for (int q = 0; q < GA; ++q) {
            int u = q * 512 + tid;
            int L = u >> 3, cp = u & 7;
            int cc = cp ^ (L & 7);
            int srow = bm + 2 * L + (cc >> 2);
            const unsigned char* src = A8 + (size_t)srow * K + (ktt << 6) + ((cc & 3) << 4);
            GLD16(src, &lds8[sbuf * BUFB + q * 8192 + ((tid >> 6) << 10)]);
        }
#pragma unroll
        for (int q = 0; q < GB; ++q) {
            int u = q * 512 + tid;
            int L = u >> 3, cp = u & 7;
            int cc = cp ^ (L & 7);
            int srow = bn + 2 * L + (cc >> 2);
            const unsigned char* src = B8 + (size_t)srow * K + (ktt << 6) + ((cc & 3) << 4);
            GLD16(src, &lds8[sbuf * BUFB + ABYTES + q * 8192 + ((tid >> 6) << 10)]);
        }
    };

    f32x4 acc[MF][NI];
#pragma unroll
    for (int i = 0; i < MF; ++i)
#pragma unroll
        for (int j = 0; j < NI; ++j) acc[i][j] = (f32x4){0.f, 0.f, 0.f, 0.f};

    stage(0, 0);
    if (KT > 1) stage(1, 1);
    if constexpr (GT == 3) { asm volatile("s_waitcnt vmcnt(3)" ::: "memory"); }
    else                   { asm volatile("s_waitcnt vmcnt(2)" ::: "memory"); }
    __builtin_amdgcn_sched_barrier(0);
    __builtin_amdgcn_s_barrier();
    __builtin_amdgcn_sched_barrier(0);

    int cur = 0, stg = 2;
    for (int kt = 0; kt < KT; ++kt) {
        const int cb = cur * BUFB;
        const bool dostage = (kt + 2) < KT;
        if (dostage) stage(kt + 2, stg);

        i64x2 av[MF], bv[NI];
#pragma unroll
        for (int mf = 0; mf < MF; ++mf) av[mf] = *(const i64x2*)&lds8[cb + aoff[mf]];
#pragma unroll
        for (int ni = 0; ni < NI; ++ni) bv[ni] = *(const i64x2*)&lds8[cb + boff[ni]];

        __builtin_amdgcn_s_setprio(1);
#pragma unroll
        for (int mf = 0; mf < MF; ++mf)
#pragma unroll
            for (int ni = 0; ni < NI; ++ni) {
                acc[mf][ni] = __builtin_amdgcn_mfma_f32_16x16x32_fp8_fp8(av[mf].x, bv[ni].x, acc[mf][ni], 0, 0, 0);
                acc[mf][ni] = __builtin_amdgcn_mfma_f32_16x16x32_fp8_fp8(av[mf].y, bv[ni].y, acc[mf][ni], 0, 0, 0);
            }
        __builtin_amdgcn_s_setprio(0);

        if (dostage) {
            if constexpr (GT == 3) { asm volatile("s_waitcnt vmcnt(3)" ::: "memory"); }
            else                   { asm volatile("s_waitcnt vmcnt(2)" ::: "memory"); }
        } else {
            asm volatile("s_waitcnt vmcnt(0)" ::: "memory");
        }
        __builtin_amdgcn_sched_barrier(0);
        __builtin_amdgcn_s_barrier();
        __builtin_amdgcn_sched_barrier(0);

        cur = (cur == 2) ? 0 : cur + 1;
        stg = (stg == 2) ? 0 : stg + 1;
    }

#pragma unroll
    for (int mf = 0; mf < MF; ++mf)
#pragma unroll
        for (int ni = 0; ni < NI; ++ni)
#pragma unroll
            for (int r = 0; r < 4; ++r) {
                int grow = bm + wm * (BM / 2) + mf * 16 + lq * 4 + r;
                int gcol = bn + wn * (BN / 4) + ni * 16 + lr;
                float v = acc[mf][ni][r];
                if (EPI == 1) {
                    if (gcol < Ntot)
                        ((unsigned short*)Cout)[(size_t)grow * ldc + coff + gcol] = f2b(v);
                } else if (EPI == 2) {
                    size_t idx = (size_t)grow * ldc + gcol;
                    ((float*)Cout)[idx] = ex[idx] + v * esc[gcol];
                } else {
                    int gc = coff + gcol;
                    ((unsigned char*)Cout)[(size_t)grow * ldc + kperm(gc)] = f2e4(v);
                }
            }
}

// ---------------- depthwise conv + silu + split, with dt/dA fused ----------------
#define TCV 64
__global__ __launch_bounds__(256) void conv_kernel(
    const unsigned short* __restrict__ ZX,   // [4096][8320] bf16
    const float* __restrict__ cwF, const float* __restrict__ cbF,
    const float* __restrict__ cwB, const float* __restrict__ cbB,
    const float* __restrict__ dtbiasF, const float* __restrict__ AlogF,
    const float* __restrict__ dtbiasB, const float* __restrict__ AlogB,
    unsigned short* __restrict__ xs,         // [2][4096][2048] bf16
    float* __restrict__ Bc, float* __restrict__ Cc,
    float* __restrict__ dtb, float* __restrict__ dAb)
{
    const int c = blockIdx.x * 256 + threadIdx.x;
    const int t0 = blockIdx.y * TCV;
    const int db = blockIdx.z;
    const int d = db >> 1, b = db & 1;

    if (c >= CDIM) {                        // dt path (32 channels)
        if (c >= CDIM + NH) return;
        const int h = c - CDIM;
        const float bias = (d ? dtbiasB : dtbiasF)[h];
        const float A = -__expf((d ? AlogB : AlogF)[h]);
        const unsigned short* zp = ZX + (size_t)d * DIP + (DI + CDIM) + h;
#pragma unroll 4
        for (int i = 0; i < TCV; ++i) {
            int t = t0 + i;
            float raw = b2f(zp[((size_t)b * LSEQ + t) * NW]);
            float xv = raw + bias;
            float dtv = (xv > 20.f) ? xv : __logf(1.f + __expf(xv));
            int idx = (db * LSEQ + t) * NH + h;
            dtb[idx] = dtv;
            dAb[idx] = __expf(dtv * A);
        }
        return;
    }

    const float* cw = d ? cwB : cwF;
    const float* cb = d ? cbB : cbF;
    float4 w = *(const float4*)&cw[c * 4];
    const float bias = cb[c];
    const unsigned short* base = ZX + (size_t)d * DIP + DI + c;

    auto ldg = [&](int t) -> float {
        return (t >= 0 && t < LSEQ) ? b2f(base[(size_t)(b * LSEQ + t) * NW]) : 0.f;
    };
    auto emit = [&](int t, float acc) {
        float v = silu_f(acc);
        const int row = b * LSEQ + t;
        if (c < DI) {
            xs[((size_t)d * RTOT + row) * DI + c] = f2b(v);
        } else if (c < DI + NSTATE) {
            Bc[((size_t)db * LSEQ + t) * NSTATE + (c - DI)] = v;
        } else {
            Cc[((size_t)db * LSEQ + t) * NSTATE + (c - DI - NSTATE)] = v;
        }
    };

    if (d == 0) {
        float v0 = ldg(t0 - 3), v1 = ldg(t0 - 2), v2 = ldg(t0 - 1), vt = ldg(t0);
#pragma unroll 4
        for (int i = 0; i < TCV; ++i) {
            float vn = (i < TCV - 1) ? ldg(t0 + i + 1) : 0.f;
            emit(t0 + i, bias + w.x * v0 + w.y * v1 + w.z * v2 + w.w * vt);
            v0 = v1; v1 = v2; v2 = vt; vt = vn;
        }
    } else {
        float v3 = ldg(t0 + TCV + 2), v2 = ldg(t0 + TCV + 1), v1 = ldg(t0 + TCV), vt = ldg(t0 + TCV - 1);
#pragma unroll 4
        for (int i = TCV - 1; i >= 0; --i) {
            float vn = (i > 0) ? ldg(t0 + i - 1) : 0.f;
            emit(t0 + i, bias + w.w * vt + w.z * v1 + w.y * v2 + w.x * v3);
            v3 = v2; v2 = v1; v1 = vt; vt = vn;
        }
    }
}

#define LD16V(dst, ptr) do { const float4* _p = (const float4*)(ptr); \
    float4 _q0 = _p[0], _q1 = _p[1], _q2 = _p[2], _q3 = _p[3]; \
    dst[0]=_q0.x; dst[1]=_q0.y; dst[2]=_q0.z; dst[3]=_q0.w; \
    dst[4]=_q1.x; dst[5]=_q1.y; dst[6]=_q1.z; dst[7]=_q1.w; \
    dst[8]=_q2.x; dst[9]=_q2.y; dst[10]=_q2.z; dst[11]=_q2.w; \
    dst[12]=_q3.x; dst[13]=_q3.y; dst[14]=_q3.z; dst[15]=_q3.w; } while (0)

#define ST16V(ptr, src) do { float4* _p = (float4*)(ptr); \
    _p[0] = make_float4(src[0],src[1],src[2],src[3]); \
    _p[1] = make_float4(src[4],src[5],src[6],src[7]); \
    _p[2] = make_float4(src[8],src[9],src[10],src[11]); \
    _p[3] = make_float4(src[12],src[13],src[14],src[15]); } while (0)

// ---------------- pass A: per-chunk zero-init state + decay product ----------------
__global__ __launch_bounds__(64) void chunk_state_kernel(
    const unsigned short* __restrict__ xs,
    const float* __restrict__ Bc,
    const float* __restrict__ dtb, const float* __restrict__ dAb,
    float* __restrict__ Sbuf,               // [128][NCH][64][16]
    float* __restrict__ Pbuf)               // [128][NCH]
{
    const int h = blockIdx.x, db = blockIdx.y, c = blockIdx.z;
    const int d = db >> 1, b = db & 1;
    const int lane = threadIdx.x;
    float hs[16];
#pragma unroll
    for (int n = 0; n < 16; ++n) hs[n] = 0.f;
    float pacc = 1.f;
    const size_t dbase = (size_t)d * RTOT;
    const int s0 = c * QCH;

    float Bs[16], xv, dtv, dAv;
    float Bn[16], xn, dtn, dAn;
    {
        const int t = d ? (LSEQ - 1 - s0) : s0;
        const size_t row = (size_t)b * LSEQ + t, rdb = (size_t)db * LSEQ + t;
        xv  = b2f(xs[(dbase + row) * DI + h * HP + lane]);
        dtv = dtb[rdb * 32 + h]; dAv = dAb[rdb * 32 + h];
        LD16V(Bs, Bc + rdb * 16);
    }
#pragma unroll 2
    for (int i = 0; i < QCH; ++i) {
        const int sn = s0 + ((i < QCH - 1) ? i + 1 : i);
        const int tn = d ? (LSEQ - 1 - sn) : sn;
        {
            const size_t rown = (size_t)b * LSEQ + tn, rdbn = (size_t)db * LSEQ + tn;
            xn  = b2f(xs[(dbase + rown) * DI + h * HP + lane]);
            dtn = dtb[rdbn * 32 + h]; dAn = dAb[rdbn * 32 + h];
            LD16V(Bn, Bc + rdbn * 16);
        }
        const float dtx = dtv * xv;
#pragma unroll
        for (int n = 0; n < 16; ++n) hs[n] = fmaf(hs[n], dAv, Bs[n] * dtx);
        pacc *= dAv;
        xv = xn; dtv = dtn; dAv = dAn;
#pragma unroll
        for (int n = 0; n < 16; ++n) Bs[n] = Bn[n];
    }
    float* Sp = Sbuf + (((size_t)(db * NH + h)) * NCH + c) * 1024 + lane * 16;
    ST16V(Sp, hs);
    if (lane == 0) Pbuf[(db * NH + h) * NCH + c] = pacc;
}

// ---------------- pass B: sequential combine over chunks (tiny) ----------------
__global__ __launch_bounds__(64) void chunk_combine_kernel(
    const float* __restrict__ Sbuf, const float* __restrict__ Pbuf,
    float* __restrict__ Hbuf)               // [128][NCH][64][16]
{
    const int idx = blockIdx.x;
    const int lane = threadIdx.x;
    float hs[16];
#pragma unroll
    for (int n = 0; n < 16; ++n) hs[n] = 0.f;
    float* H0 = Hbuf + ((size_t)idx * NCH) * 1024 + lane * 16;
    ST16V(H0, hs);
    for (int c = 0; c < NCH - 1; ++c) {
        const float* Sp = Sbuf + ((size_t)idx * NCH + c) * 1024 + lane * 16;
        float S[16];
        LD16V(S, Sp);
        const float P = Pbuf[idx * NCH + c];
#pragma unroll
        for (int n = 0; n < 16; ++n) hs[n] = fmaf(hs[n], P, S[n]);
        float* Hp = Hbuf + ((size_t)idx * NCH + c + 1) * 1024 + lane * 16;
        ST16V(Hp, hs);
    }
}

// ---------------- pass C: per-chunk scan from Hinit, emit y ----------------
__global__ __launch_bounds__(64) void chunk_scan_kernel(
    const unsigned short* __restrict__ xs,
    const float* __restrict__ Bc, const float* __restrict__ Cc,
    const float* __restrict__ dtb, const float* __restrict__ dAb,
    const float* __restrict__ DpF, const float* __restrict__ DpB,
    const float* __restrict__ Hbuf,
    unsigned short* __restrict__ ybuf)       // [2][4096][2048]
{
    const int h = blockIdx.x, db = blockIdx.y, c = blockIdx.z;
    const int d = db >> 1, b = db & 1;
    const int lane = threadIdx.x;
    const float Dp = (d ? DpB : DpF)[h];
    float hs[16];
    {
        const float* Hp = Hbuf + ((size_t)(db * NH + h) * NCH + c) * 1024 + lane * 16;
        LD16V(hs, Hp);
    }
    const size_t dbase = (size_t)d * RTOT;
    const int s0 = c * QCH;

    float Bs[16], Cs[16], xv, dtv, dAv;
    float Bn[16], Cn[16], xn, dtn, dAn;
    {
        const int t = d ? (LSEQ - 1 - s0) : s0;
        const size_t row = (size_t)b * LSEQ + t, rdb = (size_t)db * LSEQ + t;
        xv  = b2f(xs[(dbase + row) * DI + h * HP + lane]);
        dtv = dtb[rdb * 32 + h]; dAv = dAb[rdb * 32 + h];
        LD16V(Bs, Bc + rdb * 16);
        LD16V(Cs, Cc + rdb * 16);
    }
#pragma unroll 2
    for (int i = 0; i < QCH; ++i) {
        const int sn = s0 + ((i < QCH - 1) ? i + 1 : i);
        const int tn = d ? (LSEQ - 1 - sn) : sn;
        {
            const size_t rown = (size_t)b * LSEQ + tn, rdbn = (size_t)db * LSEQ + tn;
            xn  = b2f(xs[(dbase + rown) * DI + h * HP + lane]);
            dtn = dtb[rdbn * 32 + h]; dAn = dAb[rdbn * 32 + h];
            LD16V(Bn, Bc + rdbn * 16);
            LD16V(Cn, Cc + rdbn * 16);
        }
        const float dtx = dtv * xv;
        float yq[4] = {0.f, 0.f, 0.f, 0.f};
#pragma unroll
        for (int n = 0; n < 16; ++n) {
            hs[n] = fmaf(hs[n], dAv, Bs[n] * dtx);
            yq[n & 3] = fmaf(Cs[n], hs[n], yq[n & 3]);
        }
        const int t = d ? (LSEQ - 1 - (s0 + i)) : (s0 + i);
        const size_t row = (size_t)b * LSEQ + t;
        ybuf[(dbase + row) * DI + h * HP + lane] = f2b(((yq[0] + yq[1]) + (yq[2] + yq[3])) + Dp * xv);

        xv = xn; dtv = dtn; dAv = dAn;
#pragma unroll
        for (int n = 0; n < 16; ++n) { Bs[n] = Bn[n]; Cs[n] = Cn[n]; }
    }
}

// ---------------- gate (silu(z)) + RMSNorm -> fp8 K-permuted ----------------
__global__ __launch_bounds__(256) void gatenorm_kernel(
    const unsigned short* __restrict__ ybuf, const unsigned short* __restrict__ ZX,
    const float* __restrict__ nwF, const float* __restrict__ nwB,
    unsigned char* __restrict__ yg8)        // [2][4096][2048] fp8 kperm
{
    const int r = blockIdx.x;
    const int d = blockIdx.y;
    const int tid = threadIdx.x;
    const float* nw = d ? nwB : nwF;
    const int c0 = tid * 8;
    const unsigned short* yp = ybuf + ((size_t)d * RTOT + r) * DI + c0;
    const unsigned short* zp = ZX + (size_t)r * NW + d * DIP + c0;
    uint4 yv = *(const uint4*)yp;
    uint4 zv = *(const uint4*)zp;
    unsigned int yw[4] = {yv.x, yv.y, yv.z, yv.w};
    unsigned int zw[4] = {zv.x, zv.y, zv.z, zv.w};
    float g[8]; float ss = 0.f;
#pragma unroll
    for (int i = 0; i < 8; ++i) {
        unsigned short yu = (i & 1) ? (unsigned short)(yw[i >> 1] >> 16) : (unsigned short)(yw[i >> 1] & 0xffff);
        unsigned short zu = (i & 1) ? (unsigned short)(zw[i >> 1] >> 16) : (unsigned short)(zw[i >> 1] & 0xffff);
        float y = b2f(yu), z = b2f(zu);
        float gv = y * silu_f(z);
        g[i] = gv; ss += gv * gv;
    }
#pragma unroll
    for (int m = 1; m < 64; m <<= 1) ss += __shfl_xor(ss, m, 64);
    __shared__ float red[4];
    if ((tid & 63) == 0) red[tid >> 6] = ss;
    __syncthreads();
    float tot = red[0] + red[1] + red[2] + red[3];
    float sc = rsqrtf(tot * (1.f / 2048.f) + 1e-5f);
    unsigned char o[8];
#pragma unroll
    for (int i = 0; i < 8; ++i) o[i] = f2e4(g[i] * sc * nw[c0 + i]);
    const int pos = (c0 & ~63) | (((c0 >> 3) & 3) << 4) | (((c0 >> 5) & 1) << 3);
    *(uint2*)(yg8 + ((size_t)d * RTOT + r) * DI + pos) = *(uint2*)o;
}

// ---------------- host ----------------
extern "C" void kernel_launch(void* const* d_in, const int* in_sizes, int n_in,
                              void* d_out, int out_size, void* d_ws, size_t ws_size,
                              hipStream_t stream)
{
    const float* x     = (const float*)d_in[0];
    const float* fin   = (const float*)d_in[1];
    const float* fcw   = (const float*)d_in[2];
    const float* fcb   = (const float*)d_in[3];
    const float* fdtb  = (const float*)d_in[4];
    const float* fAlog = (const float*)d_in[5];
    const float* fDp   = (const float*)d_in[6];
    const float* fnw   = (const float*)d_in[7];
    const float* fout  = (const float*)d_in[8];
    const float* bin   = (const float*)d_in[9];
    const float* bcw   = (const float*)d_in[10];
    const float* bcb   = (const float*)d_in[11];
    const float* bdtb  = (const float*)d_in[12];
    const float* bAlog = (const float*)d_in[13];
    const float* bDp   = (const float*)d_in[14];
    const float* bnw   = (const float*)d_in[15];
    const float* bout  = (const float*)d_in[16];
    const float* lw    = (const float*)d_in[17];
    const float* lsc   = (const float*)d_in[18];

    char* w = (char*)d_ws;
    auto alloc = [&](size_t bytes) { char* p = w; w += (bytes + 255) & ~(size_t)255; return p; };
    unsigned char*  xb8  = (unsigned char*)alloc((size_t)RTOT * DM);        // 4.2 MB
    unsigned char*  win8 = (unsigned char*)alloc((size_t)NWP * DM);         // 8.65 MB
    unsigned char*  wo8  = (unsigned char*)alloc((size_t)2 * DM * DI);      // 4.2 MB
    unsigned char*  wl8  = (unsigned char*)alloc((size_t)DM * DI);          // 2.1 MB
    unsigned short* zx  = (unsigned short*)alloc((size_t)RTOT * NW * 2);    // 68 MB
    unsigned short* xs  = (unsigned short*)alloc((size_t)2 * RTOT * DI * 2);// 33.5 MB
    float* Bc  = (float*)alloc((size_t)2 * RTOT * NSTATE * 4);
    float* Cc  = (float*)alloc((size_t)2 * RTOT * NSTATE * 4);
    float* dtb = (float*)alloc((size_t)2 * RTOT * NH * 4);
    float* dAb = (float*)alloc((size_t)2 * RTOT * NH * 4);
    unsigned short* yb  = (unsigned short*)alloc((size_t)2 * RTOT * DI * 2);// 33.5 MB
    unsigned char*  yg8 = (unsigned char*)alloc((size_t)2 * RTOT * DI);     // 16.8 MB
    unsigned char*  hbi8= (unsigned char*)alloc((size_t)RTOT * DI);         // 8.4 MB
    float* Pbuf = (float*)alloc((size_t)128 * NCH * 4);
    float* Sbuf = (float*)alloc((size_t)128 * NCH * 1024 * 4);              // 16.8 MB
    float* Hbuf = (float*)alloc((size_t)128 * NCH * 1024 * 4);              // 16.8 MB
    (void)ws_size; (void)in_sizes; (void)n_in; (void)out_size;

    // all f32 -> fp8 K-permuted converts in ONE dispatch
    Cvt8Jobs j;
    j.s0[0] = x;    j.s1[0] = x;    j.dst[0] = xb8;  j.rows0[0] = RTOT; j.rows1[0] = 0;    j.rowstot[0] = RTOT; j.shift[0] = 7;
    j.s0[1] = fin;  j.s1[1] = bin;  j.dst[1] = win8; j.rows0[1] = DIP;  j.rows1[1] = DIP;  j.rowstot[1] = NWP;  j.shift[1] = 7;
    j.s0[2] = fout; j.s1[2] = bout; j.dst[2] = wo8;  j.rows0[2] = DM;   j.rows1[2] = DM;   j.rowstot[2] = 2 * DM; j.shift[2] = 8;
    j.s0[3] = lw;   j.s1[3] = lw;   j.dst[3] = wl8;  j.rows0[3] = DM;   j.rows1[3] = 0;    j.rowstot[3] = DM;   j.shift[3] = 8;
    cvt8b_kernel<<<dim3((NWP * 128 + 255) / 256, 4), 256, 0, stream>>>(j);

    // GEMM A (fp8): zxbcdt both dirs. M=4096, N=8320(pad 8448), K=1024
    gemm8_kernel<128, 256, 1><<<dim3(NWP / 256, RTOT / 128), 512, 0, stream>>>(
        xb8, win8, nullptr, nullptr, zx, NW, DM, NW, 0, 0, nullptr, nullptr);

    // conv + silu + split + fused dt/dA
    conv_kernel<<<dim3((CDIM + NH + 255) / 256, LSEQ / TCV, 4), 256, 0, stream>>>(
        zx, fcw, fcb, bcw, bcb, fdtb, fAlog, bdtb, bAlog, xs, Bc, Cc, dtb, dAb);

    // chunked scan: A) per-chunk states, B) combine, C) per-chunk scan+y
    chunk_state_kernel<<<dim3(NH, 4, NCH - 1), 64, 0, stream>>>(
        xs, Bc, dtb, dAb, Sbuf, Pbuf);
    chunk_combine_kernel<<<128, 64, 0, stream>>>(Sbuf, Pbuf, Hbuf);
    chunk_scan_kernel<<<dim3(NH, 4, NCH), 64, 0, stream>>>(
        xs, Bc, Cc, dtb, dAb, fDp, bDp, Hbuf, yb);

    // gate + RMSNorm -> fp8 kperm
    gatenorm_kernel<<<dim3(RTOT, 2), 256, 0, stream>>>(yb, zx, fnw, bnw, yg8);

    // GEMM B (fp8): out_proj both dirs fused (grid.z=2). M=4096, N=1024/dir, K=2048
    // output: hbi8 fp8 kperm, cols [0,1024) fwd | [1024,2048) bwd
    gemm8_kernel<128, 128, 3><<<dim3(DM / 128, RTOT / 128, 2), 512, 0, stream>>>(
        yg8, wo8, yg8 + (size_t)RTOT * DI, wo8 + (size_t)DM * DI,
        hbi8, DM, DI, DI, 0, DM, nullptr, nullptr);

    // GEMM C (fp8): layer out proj + residual epilogue. M=4096, N=1024, K=2048
    gemm8_kernel<128, 128, 2><<<dim3(DM / 128, RTOT / 128), 512, 0, stream>>>(
        hbi8, wl8, nullptr, nullptr, d_out, DM, DI, DM, 0, 0, x, lsc);
}